// Round 2
// baseline (322.709 us; speedup 1.0000x reference)
//
#include <hip/hip_runtime.h>

#define NPIX 4096
#define CDIM 128
#define BATCH 8
#define EPSN 1e-5f
#define LOG2E 1.44269504088896340736f

typedef __attribute__((ext_vector_type(8))) short short8;
typedef __attribute__((ext_vector_type(4))) float f32x4;
typedef __attribute__((ext_vector_type(16))) float f32x16;

__device__ __forceinline__ float sigmoidf_(float x) { return 1.f / (1.f + __expf(-x)); }

__device__ __forceinline__ unsigned short f2b(float f) {
    unsigned int u = __float_as_uint(f);
    unsigned int r = (u + 0x7FFF + ((u >> 16) & 1)) >> 16;  // RNE
    return (unsigned short)r;
}
__device__ __forceinline__ float b2f(unsigned short u) {
    return __uint_as_float((unsigned int)u << 16);
}

// exchange: after call, a = {a.lo, b.lo->hi}, b = {a.hi->lo, b.hi}
// (v_permlane32_swap_b32 swaps upper 32 lanes of a with lower 32 lanes of b)
__device__ __forceinline__ void pl32swap(unsigned int& a, unsigned int& b) {
    asm("v_permlane32_swap_b32 %0, %1" : "+v"(a), "+v"(b));
}

// window token -> pixel index
__device__ __forceinline__ int tok2pix(int mode, int wi, int l) {
    return (mode == 0) ? ((l >> 2) * 64 + wi * 4 + (l & 3))
                       : ((wi * 4 + (l >> 6)) * 64 + (l & 63));
}

// ---------------- weight conversion / reorder / transposes / gstats zeroing ----------------
// q0/q1 weight+bias groups pre-scaled by log2(e) so attention can use native exp2.
__global__ __launch_bounds__(256) void convert_w_kernel(const float* __restrict__ qkv_w,
                                                        const float* __restrict__ mlp1_w,
                                                        const float* __restrict__ mlp2_w,
                                                        const float* __restrict__ actp_w,
                                                        const float* __restrict__ inp_w,
                                                        const float* __restrict__ outp_w,
                                                        const float* __restrict__ qkv_b,
                                                        const float* __restrict__ eaax_w,
                                                        const float* __restrict__ eaax_b,
                                                        const float* __restrict__ eaay_w,
                                                        const float* __restrict__ eaay_b,
                                                        const float* __restrict__ cpe1_w,
                                                        const float* __restrict__ dwc_w,
                                                        const float* __restrict__ cpe2_w,
                                                        const float* __restrict__ actp_b,
                                                        const float* __restrict__ inp_b,
                                                        unsigned short* __restrict__ dst,
                                                        float* __restrict__ qb_r,
                                                        float* __restrict__ wsT,
                                                        float* __restrict__ bsum,
                                                        float* __restrict__ cpe1T,
                                                        float* __restrict__ dwcT,
                                                        float* __restrict__ cpe2T,
                                                        float* __restrict__ abi,
                                                        float* __restrict__ gstats) {
    int i = blockIdx.x * 256 + threadIdx.x;
    if (i >= 267776) {
        if (i < 269824) gstats[i - 267776] = 0.f;
        return;
    }
    if (i < 262144) {
        float v;
        if (i < 81920) {
            int o = i >> 7, c = i & 127;              // reordered: o_new = g*128+cc
            int g = o >> 7;
            v = qkv_w[(size_t)(5 * (o & 127) + g) * 128 + c];
            if (g == 0 || g == 3) v *= LOG2E;         // q0/q1 pre-scale for exp2
        } else if (i < 147456) v = mlp1_w[i - 81920];
        else if (i < 212992)   v = mlp2_w[i - 147456];
        else if (i < 229376)   v = actp_w[i - 212992];
        else if (i < 245760)   v = inp_w[i - 229376];
        else                   v = outp_w[i - 245760];
        dst[i] = f2b(v);
    } else {
        int j = i - 262144;
        if (j < 640) {
            int g = j >> 7;
            float v = qkv_b[5 * (j & 127) + g];
            if (g == 0 || g == 3) v *= LOG2E;
            qb_r[j] = v;
        }
        else if (j < 1792) {
            int idx = j - 640; int k = idx >> 7, c = idx & 127;
            wsT[idx] = eaax_w[c * 9 + k] + eaay_w[c * 9 + k];
        } else if (j < 1920) bsum[j - 1792] = eaax_b[j - 1792] + eaay_b[j - 1792];
        else if (j < 3072) {
            int idx = j - 1920; int k = idx >> 7, c = idx & 127;
            cpe1T[idx] = cpe1_w[c * 9 + k];
        } else if (j < 4224) {
            int idx = j - 3072; int k = idx >> 7, c = idx & 127;
            dwcT[idx] = dwc_w[c * 9 + k];
        } else if (j < 5376) {
            int idx = j - 4224; int k = idx >> 7, c = idx & 127;
            cpe2T[idx] = cpe2_w[c * 9 + k];
        } else {
            int idx = j - 5376;
            abi[idx] = (idx < 128) ? actp_b[idx] : inp_b[idx - 128];
        }
    }
}

// ---------------- per-(b,c) mean over HW (x is NCHW input) ----------------
__global__ __launch_bounds__(256) void mean_bc_kernel(const float* __restrict__ x,
                                                      float* __restrict__ mean) {
    __shared__ float sb[4];
    int bc = blockIdx.x;
    const float* p = x + (size_t)bc * NPIX;
    float s = 0.f;
    for (int i = threadIdx.x; i < NPIX; i += 256) s += p[i];
#pragma unroll
    for (int off = 32; off > 0; off >>= 1) s += __shfl_down(s, off, 64);
    if ((threadIdx.x & 63) == 0) sb[threadIdx.x >> 6] = s;
    __syncthreads();
    if (threadIdx.x == 0) mean[bc] = (sb[0] + sb[1] + sb[2] + sb[3]) * (1.f / (float)NPIX);
}

// ---------------- ESA+ECA fused (gate computed inline) with NCHW->NHWC transpose ----------------
__global__ __launch_bounds__(256) void esa_tr_kernel(const float* __restrict__ x,
                                                     const float* __restrict__ mean,
                                                     const float* __restrict__ w5,
                                                     const float* __restrict__ alpha_p,
                                                     float* __restrict__ y) {
    __shared__ float tile[128][65];
    __shared__ float smx[4][64], smn[4][64], ssc[64], gat[128];
    int b = blockIdx.y, p0 = blockIdx.x * 64;
    int tx = threadIdx.x, pl = tx & 63, part = tx >> 6;
    const float* xb = x + (size_t)b * CDIM * NPIX;
    const float* mb = mean + b * CDIM;
    for (int c = part; c < CDIM; c += 4)
        tile[c][pl] = xb[(size_t)c * NPIX + p0 + pl];
    __syncthreads();
    float mx = -1e30f, mn = 1e30f;
#pragma unroll
    for (int cc = 0; cc < 32; ++cc) {
        int c = part * 32 + cc;
        float v = tile[c][pl] - mb[c];
        mx = fmaxf(mx, v); mn = fminf(mn, v);
    }
    smx[part][pl] = mx; smn[part][pl] = mn;
    __syncthreads();
    if (tx < 128) {
        float s = 0.f;
#pragma unroll
        for (int k = 0; k < 5; ++k) {
            int cc = tx + k - 2;
            if (cc >= 0 && cc < CDIM) s += w5[k] * mb[cc];
        }
        gat[tx] = sigmoidf_(s);
    }
    if (part == 0) {
        float m1 = fmaxf(fmaxf(smx[0][pl], smx[1][pl]), fmaxf(smx[2][pl], smx[3][pl]));
        float m2 = fminf(fminf(smn[0][pl], smn[1][pl]), fminf(smn[2][pl], smn[3][pl]));
        float a = alpha_p[0];
        ssc[pl] = sigmoidf_(m1) * a + sigmoidf_(m2) * (1.f - a);
    }
    __syncthreads();
    int c2 = tx & 127, pr = tx >> 7;
    float* yb = y + ((size_t)b * NPIX + p0) * CDIM;
    float gv = gat[c2];
    for (int p = pr; p < 64; p += 2)
        yb[(size_t)p * CDIM + c2] = tile[c2][p] * (gv + ssc[p]);
}

// ---------------- NHWC f32 dwconv3 + residual + fused PER-BATCH GN stats (8 spread slots) ----------------
__global__ __launch_bounds__(256) void cpe_f32_kernel(const float* __restrict__ in,
                                                      const float* __restrict__ wT,
                                                      const float* __restrict__ bias,
                                                      float* __restrict__ out,
                                                      float* __restrict__ stats) {
    __shared__ float sb[8];
    int b = blockIdx.y, tx = threadIdx.x;
    int cg = tx & 15, pp = tx >> 4;
    int p = blockIdx.x * 16 + pp;
    int xx = p & 63, yy = p >> 6;
    int c0 = cg * 8;
    float acc[8], ctr[8];
#pragma unroll
    for (int j = 0; j < 8; ++j) acc[j] = bias[c0 + j];
#pragma unroll
    for (int dy = -1; dy <= 1; ++dy) {
        int y2 = yy + dy;
        if (y2 < 0 || y2 >= 64) continue;
#pragma unroll
        for (int dx = -1; dx <= 1; ++dx) {
            int x2 = xx + dx;
            if (x2 < 0 || x2 >= 64) continue;
            const float* ip = &in[((size_t)b * NPIX + y2 * 64 + x2) * 128 + c0];
            float4 v0 = *(const float4*)ip;
            float4 v1 = *(const float4*)(ip + 4);
            const float* wr = wT + ((dy + 1) * 3 + dx + 1) * 128 + c0;
            acc[0] += v0.x * wr[0]; acc[1] += v0.y * wr[1];
            acc[2] += v0.z * wr[2]; acc[3] += v0.w * wr[3];
            acc[4] += v1.x * wr[4]; acc[5] += v1.y * wr[5];
            acc[6] += v1.z * wr[6]; acc[7] += v1.w * wr[7];
            if (dy == 0 && dx == 0) {
                ctr[0] = v0.x; ctr[1] = v0.y; ctr[2] = v0.z; ctr[3] = v0.w;
                ctr[4] = v1.x; ctr[5] = v1.y; ctr[6] = v1.z; ctr[7] = v1.w;
            }
        }
    }
    float s = 0.f, s2 = 0.f;
    float r[8];
#pragma unroll
    for (int j = 0; j < 8; ++j) {
        r[j] = ctr[j] + acc[j];
        s += r[j]; s2 += r[j] * r[j];
    }
    float* op = &out[((size_t)b * NPIX + p) * 128 + c0];
    *(float4*)op = make_float4(r[0], r[1], r[2], r[3]);
    *(float4*)(op + 4) = make_float4(r[4], r[5], r[6], r[7]);
#pragma unroll
    for (int off = 32; off > 0; off >>= 1) {
        s += __shfl_down(s, off, 64);
        s2 += __shfl_down(s2, off, 64);
    }
    int wv = tx >> 6;
    if ((tx & 63) == 0) { sb[wv] = s; sb[4 + wv] = s2; }
    __syncthreads();
    if (tx == 0) {
        int slot = (b * 8 + (blockIdx.x & 7)) * 16;
        atomicAdd(&stats[slot], sb[0] + sb[1] + sb[2] + sb[3]);
        atomicAdd(&stats[slot + 1], sb[4] + sb[5] + sb[6] + sb[7]);
    }
}

// ---------------- NHWC bf16 dwconv3 + bias + relu -> bf16 ----------------
__global__ __launch_bounds__(256) void dwc_bf16_kernel(const unsigned short* __restrict__ in,
                                                       const float* __restrict__ wT,
                                                       const float* __restrict__ bias,
                                                       unsigned short* __restrict__ out) {
    int b = blockIdx.y, tx = threadIdx.x;
    int cg = tx & 15, pp = tx >> 4;
    int p = blockIdx.x * 16 + pp;
    int xx = p & 63, yy = p >> 6;
    int c0 = cg * 8;
    float acc[8];
#pragma unroll
    for (int j = 0; j < 8; ++j) acc[j] = bias[c0 + j];
#pragma unroll
    for (int dy = -1; dy <= 1; ++dy) {
        int y2 = yy + dy;
        if (y2 < 0 || y2 >= 64) continue;
#pragma unroll
        for (int dx = -1; dx <= 1; ++dx) {
            int x2 = xx + dx;
            if (x2 < 0 || x2 >= 64) continue;
            unsigned short v[8];
            *(uint4*)v = *(const uint4*)&in[((size_t)b * NPIX + y2 * 64 + x2) * 128 + c0];
            const float* wr = wT + ((dy + 1) * 3 + dx + 1) * 128 + c0;
#pragma unroll
            for (int j = 0; j < 8; ++j) acc[j] += b2f(v[j]) * wr[j];
        }
    }
    unsigned short o[8];
#pragma unroll
    for (int j = 0; j < 8; ++j) o[j] = f2b(fmaxf(acc[j], 0.f));
    *(uint4*)&out[((size_t)b * NPIX + p) * 128 + c0] = *(uint4*)o;
}

// ---------------- conv1x1 via bf16 MFMA, 64px tile, ntile x 128-out tiles per block ----------------
// B (activations) staged+converted ONCE per block; output tiles looped in-kernel.
// Eliminates the per-blockIdx.y B re-stage (qkv was 5x, mlp1 4x — incl. redundant GN apply VALU).
__global__ __launch_bounds__(256) void conv_mfma_kernel(const unsigned short* __restrict__ in_t,
                                                        const float* __restrict__ in_f32,
                                                        const float* __restrict__ gst,
                                                        const float* __restrict__ gg,
                                                        const float* __restrict__ gbta,
                                                        const unsigned short* __restrict__ w,
                                                        const float* __restrict__ bias,
                                                        const float* __restrict__ res,
                                                        float* __restrict__ out,
                                                        unsigned short* __restrict__ out_t,
                                                        unsigned short* __restrict__ out_t2,
                                                        int Cin, int Cout, int relu, int nchw,
                                                        int ntile) {
    __shared__ __align__(16) unsigned short A_s[128][136];
    __shared__ __align__(16) unsigned short B_s[64][136];
    int b = blockIdx.z, p0 = blockIdx.x * 64;
    int tx = threadIdx.x;
    int wave = tx >> 6, lane = tx & 63;
    int wm = wave & 1, wn = wave >> 1;
    int quad = lane >> 4, l16 = lane & 15;

    float mu = 0.f, rr = 1.f;
    if (in_f32) {
        float su = 0.f, sq = 0.f;
#pragma unroll
        for (int sl = 0; sl < 8; ++sl) {
            su += gst[(b * 8 + sl) * 16];
            sq += gst[(b * 8 + sl) * 16 + 1];
        }
        const float n = 1.f / (float)(CDIM * NPIX);
        mu = su * n;
        float var = sq * n - mu * mu;
        rr = rsqrtf(var + EPSN);
    }

    // ---- stage B once when Cin==128 (all multi-tile cases) ----
    if (Cin == 128) {
        if (in_f32) {
#pragma unroll
            for (int j = 0; j < 4; ++j) {
                int idx = tx + 256 * j;
                int row = idx >> 4, c16 = idx & 15;
                int ch = c16 * 8;
                const float* ip = &in_f32[((size_t)b * NPIX + p0 + row) * 128 + ch];
                float4 v0 = *(const float4*)ip;
                float4 v1 = *(const float4*)(ip + 4);
                unsigned short o[8];
                o[0] = f2b((v0.x - mu) * rr * gg[ch + 0] + gbta[ch + 0]);
                o[1] = f2b((v0.y - mu) * rr * gg[ch + 1] + gbta[ch + 1]);
                o[2] = f2b((v0.z - mu) * rr * gg[ch + 2] + gbta[ch + 2]);
                o[3] = f2b((v0.w - mu) * rr * gg[ch + 3] + gbta[ch + 3]);
                o[4] = f2b((v1.x - mu) * rr * gg[ch + 4] + gbta[ch + 4]);
                o[5] = f2b((v1.y - mu) * rr * gg[ch + 5] + gbta[ch + 5]);
                o[6] = f2b((v1.z - mu) * rr * gg[ch + 6] + gbta[ch + 6]);
                o[7] = f2b((v1.w - mu) * rr * gg[ch + 7] + gbta[ch + 7]);
                *(uint4*)&B_s[row][c16 * 8] = *(uint4*)o;
            }
        } else {
#pragma unroll
            for (int j = 0; j < 4; ++j) {
                int idx = tx + 256 * j;
                int row = idx >> 4, c16 = idx & 15;
                *(uint4*)&B_s[row][c16 * 8] =
                    *(const uint4*)&in_t[((size_t)b * NPIX + p0 + row) * Cin + c16 * 8];
            }
        }
    }

    for (int t = 0; t < ntile; ++t) {
        int o0 = t * 128;

        f32x4 acc[4][2];
#pragma unroll
        for (int mt = 0; mt < 4; ++mt) {
#pragma unroll
            for (int r = 0; r < 4; ++r) {
                float bv = bias[o0 + wm * 64 + mt * 16 + quad * 4 + r];
#pragma unroll
                for (int nt = 0; nt < 2; ++nt) acc[mt][nt][r] = bv;
            }
        }

        for (int k0 = 0; k0 < Cin; k0 += 128) {
#pragma unroll
            for (int j = 0; j < 8; ++j) {
                int idx = tx + 256 * j;
                int row = idx >> 4, c16 = idx & 15;
                *(uint4*)&A_s[row][c16 * 8] =
                    *(const uint4*)&w[(size_t)(o0 + row) * Cin + k0 + c16 * 8];
            }
            if (Cin != 128) {
#pragma unroll
                for (int j = 0; j < 4; ++j) {
                    int idx = tx + 256 * j;
                    int row = idx >> 4, c16 = idx & 15;
                    *(uint4*)&B_s[row][c16 * 8] =
                        *(const uint4*)&in_t[((size_t)b * NPIX + p0 + row) * Cin + k0 + c16 * 8];
                }
            }
            __syncthreads();
#pragma unroll
            for (int ks = 0; ks < 128; ks += 32) {
                short8 af[4], bf[2];
#pragma unroll
                for (int mt = 0; mt < 4; ++mt)
                    af[mt] = *(const short8*)&A_s[wm * 64 + mt * 16 + l16][ks + quad * 8];
#pragma unroll
                for (int nt = 0; nt < 2; ++nt)
                    bf[nt] = *(const short8*)&B_s[wn * 32 + nt * 16 + l16][ks + quad * 8];
#pragma unroll
                for (int mt = 0; mt < 4; ++mt)
#pragma unroll
                    for (int nt = 0; nt < 2; ++nt)
                        acc[mt][nt] = __builtin_amdgcn_mfma_f32_16x16x32_bf16(
                            af[mt], bf[nt], acc[mt][nt], 0, 0, 0);
            }
            __syncthreads();
        }

        int dorelu = (relu == 1) || (relu == 2 && t == 0);
        if (out_t) {
#pragma unroll
            for (int mt = 0; mt < 4; ++mt) {
#pragma unroll
                for (int nt = 0; nt < 2; ++nt) {
                    int p = p0 + wn * 32 + nt * 16 + l16;
                    int ob = o0 + wm * 64 + mt * 16 + quad * 4;
                    unsigned short* dbuf = out_t;
                    int oc = ob;
                    if (out_t2 && o0 >= 128) { dbuf = out_t2; oc = ob - 128; }
                    ushort4 u;
                    float v0 = acc[mt][nt][0], v1 = acc[mt][nt][1];
                    float v2 = acc[mt][nt][2], v3 = acc[mt][nt][3];
                    if (dorelu) { v0 = fmaxf(v0, 0.f); v1 = fmaxf(v1, 0.f);
                                  v2 = fmaxf(v2, 0.f); v3 = fmaxf(v3, 0.f); }
                    u.x = f2b(v0); u.y = f2b(v1); u.z = f2b(v2); u.w = f2b(v3);
                    *(ushort4*)&dbuf[((size_t)b * NPIX + p) * Cout + oc] = u;
                }
            }
        } else if (!nchw) {
#pragma unroll
            for (int mt = 0; mt < 4; ++mt) {
#pragma unroll
                for (int nt = 0; nt < 2; ++nt) {
                    int p = p0 + wn * 32 + nt * 16 + l16;
                    int ob = o0 + wm * 64 + mt * 16 + quad * 4;
                    size_t ix = ((size_t)b * NPIX + p) * Cout + ob;
                    float4 v = make_float4(acc[mt][nt][0], acc[mt][nt][1],
                                           acc[mt][nt][2], acc[mt][nt][3]);
                    if (dorelu) { v.x = fmaxf(v.x, 0.f); v.y = fmaxf(v.y, 0.f);
                                  v.z = fmaxf(v.z, 0.f); v.w = fmaxf(v.w, 0.f); }
                    if (res) {
                        float4 rv = *(const float4*)&res[ix];
                        v.x += rv.x; v.y += rv.y; v.z += rv.z; v.w += rv.w;
                    }
                    *(float4*)&out[ix] = v;
                }
            }
        } else {
            float* outb = out + (size_t)b * Cout * NPIX;
#pragma unroll
            for (int mt = 0; mt < 4; ++mt) {
#pragma unroll
                for (int nt = 0; nt < 2; ++nt) {
                    int p = p0 + wn * 32 + nt * 16 + l16;
                    int ob = o0 + wm * 64 + mt * 16 + quad * 4;
                    float4 rv = make_float4(0.f, 0.f, 0.f, 0.f);
                    if (res) rv = *(const float4*)&res[((size_t)b * NPIX + p) * 128 + ob];
#pragma unroll
                    for (int r = 0; r < 4; ++r) {
                        float v = acc[mt][nt][r];
                        if (dorelu) v = fmaxf(v, 0.f);
                        v += (r == 0 ? rv.x : r == 1 ? rv.y : r == 2 ? rv.z : rv.w);
                        outb[(size_t)(ob + r) * NPIX + p] = v;
                    }
                }
            }
        }
    }
}

// ---------------- MFMA window attention, both orientations in one launch ----------------
// q pre-scaled by log2(e) -> native exp2; row-sum via ones-row at PV A row 16 (o_acc[8]).
// k pixel offsets hoisted out of the qi loop (pofs[8], fully unrolled -> registers;
// loads stay address-independent for MLP — serial pointer-increment form was slower, round 11).
// P-fragment redistribution: v_permlane32_swap_b32 replaces 8x ds_bpermute (__shfl_xor)
// + 8x cndmask (divergent half select). V tile padded to 32 rows (row16=ones, 17-31=0)
// so the PV A-operand is two unconditional ds_read_b128 (no divergent 3-way branch).
__global__ __launch_bounds__(256) void attn_dual_kernel(const unsigned short* __restrict__ t_t,
                                                        float* __restrict__ a0,
                                                        float* __restrict__ a1) {
    __shared__ __align__(16) unsigned short Vt[32][264];
    int wi = blockIdx.x, head = blockIdx.y;
    int z = blockIdx.z;
    int b = z >> 1, which = z & 1;
    int qoff = which ? 384 : 0;
    int koff = which ? 512 : 128;
    int mode = which;
    float* a_out = which ? a1 : a0;
    int tx = threadIdx.x;
    int wave = tx >> 6, l = tx & 63;
    int l32 = l & 31, half = l >> 5;
    const size_t base = (size_t)b * NPIX;
    const int hc = head * 16;

    {
        int p = tok2pix(mode, wi, tx);
        const unsigned short* vp = &t_t[(base + p) * 640 + 256 + hc];
        unsigned short tmp[16];
        *(uint4*)&tmp[0] = *(const uint4*)vp;
        *(uint4*)&tmp[8] = *(const uint4*)(vp + 8);
#pragma unroll
        for (int d = 0; d < 16; ++d) Vt[d][tx] = tmp[d];
        Vt[16][tx] = (unsigned short)0x3F80;  // bf16 1.0 — row-sum row
#pragma unroll
        for (int d = 17; d < 32; ++d) Vt[d][tx] = 0;
    }
    __syncthreads();

    f32x16 zzero;
#pragma unroll
    for (int r = 0; r < 16; ++r) zzero[r] = 0.f;

    // per-lane pixel offsets (in ushort units) for the 8 token chunks
    int pofs[8];
#pragma unroll
    for (int nt = 0; nt < 8; ++nt)
        pofs[nt] = tok2pix(mode, wi, nt * 32 + l32) * 640;

    const unsigned short* tb = t_t + base * 640 + hc + half * 8;
    const unsigned short* kb = tb + koff;
    const unsigned short* qb = tb + qoff;

#pragma unroll
    for (int qi = 0; qi < 2; ++qi) {
        int qs = qi * 4 + wave;
        int qp = tok2pix(mode, wi, qs * 32 + l32);
        short8 qf = *(const short8*)&qb[(size_t)qp * 640];
        f32x16 o_acc = zzero;
#pragma unroll
        for (int nt = 0; nt < 8; ++nt) {
            short8 kf = *(const short8*)&kb[pofs[nt]];
            f32x16 s = __builtin_amdgcn_mfma_f32_32x32x16_bf16(kf, qf, zzero, 0, 0, 0);
            unsigned int pk[8];
#pragma unroll
            for (int i = 0; i < 8; ++i) {
                float e0 = __builtin_amdgcn_exp2f(s[2 * i]);
                float e1 = __builtin_amdgcn_exp2f(s[2 * i + 1]);
                pk[i] = __builtin_amdgcn_perm(__float_as_uint(e1), __float_as_uint(e0),
                                              0x07060302u);
            }
            // redistribute halves: (u0[0],u0[2]) = swap(pk0,pk2), etc.
            pl32swap(pk[0], pk[2]);
            pl32swap(pk[1], pk[3]);
            pl32swap(pk[4], pk[6]);
            pl32swap(pk[5], pk[7]);
            short8 vf0 = *(const short8*)&Vt[l32][nt * 32 + half * 8];
            short8 vf1 = *(const short8*)&Vt[l32][nt * 32 + 16 + half * 8];
            unsigned int u0[4] = {pk[0], pk[1], pk[2], pk[3]};
            unsigned int u1[4] = {pk[4], pk[5], pk[6], pk[7]};
            o_acc = __builtin_amdgcn_mfma_f32_32x32x16_bf16(vf0, *(short8*)u0, o_acc, 0, 0, 0);
            o_acc = __builtin_amdgcn_mfma_f32_32x32x16_bf16(vf1, *(short8*)u1, o_acc, 0, 0, 0);
        }
        // row 16 of PV output = sum_t P[t][col]  (half-0 lanes, r=8)
        float rs = o_acc[8];
        rs += __shfl_xor(rs, 32, 64);
        float rinv = 1.f / rs;
        // d = (r&3) + 8*(r>>2) + 4*half  ->  two contiguous float4 runs
        float* dst = a_out + (base + qp) * 128 + hc + 4 * half;
        float4 s0 = make_float4(o_acc[0] * rinv, o_acc[1] * rinv,
                                o_acc[2] * rinv, o_acc[3] * rinv);
        float4 s1 = make_float4(o_acc[4] * rinv, o_acc[5] * rinv,
                                o_acc[6] * rinv, o_acc[7] * rinv);
        *(float4*)dst = s0;
        *(float4*)(dst + 8) = s1;
    }
}

// ---------------- m_t = bf16((a0 + a1 + cpe(v0)) * act_res)  (all NHWC) ----------------
__global__ __launch_bounds__(256) void mul3_cpe_kernel(const float* __restrict__ a0,
                                                       const float* __restrict__ a1,
                                                       const unsigned short* __restrict__ act,
                                                       const unsigned short* __restrict__ t_t,
                                                       const float* __restrict__ wT,
                                                       const float* __restrict__ bsum,
                                                       unsigned short* __restrict__ dst) {
    int b = blockIdx.y;
    int tx = threadIdx.x;
    int cg = tx & 15, pp = tx >> 4;
    int p = blockIdx.x * 16 + pp;
    int xx = p & 63, yy = p >> 6;
    int c0 = cg * 8;
    float acc[8];
#pragma unroll
    for (int j = 0; j < 8; ++j) acc[j] = bsum[c0 + j];
#pragma unroll
    for (int dy = -1; dy <= 1; ++dy) {
        int y2 = yy + dy;
        if (y2 < 0 || y2 >= 64) continue;
#pragma unroll
        for (int dx = -1; dx <= 1; ++dx) {
            int x2 = xx + dx;
            if (x2 < 0 || x2 >= 64) continue;
            int pn = y2 * 64 + x2;
            unsigned short v[8];
            *(uint4*)v = *(const uint4*)&t_t[((size_t)b * NPIX + pn) * 640 + 256 + c0];
            const float* wr = wT + ((dy + 1) * 3 + dx + 1) * 128 + c0;
#pragma unroll
            for (int j = 0; j < 8; ++j) acc[j] += b2f(v[j]) * wr[j];
        }
    }
    size_t base = ((size_t)b * NPIX + p) * 128 + c0;
    float4 x0 = *(const float4*)&a0[base];
    float4 x1 = *(const float4*)&a0[base + 4];
    float4 y0 = *(const float4*)&a1[base];
    float4 y1 = *(const float4*)&a1[base + 4];
    unsigned short t[8];
    *(uint4*)t = *(const uint4*)&act[base];
    unsigned short r[8];
    r[0] = f2b((x0.x + y0.x + acc[0]) * b2f(t[0]));
    r[1] = f2b((x0.y + y0.y + acc[1]) * b2f(t[1]));
    r[2] = f2b((x0.z + y0.z + acc[2]) * b2f(t[2]));
    r[3] = f2b((x0.w + y0.w + acc[3]) * b2f(t[3]));
    r[4] = f2b((x1.x + y1.x + acc[4]) * b2f(t[4]));
    r[5] = f2b((x1.y + y1.y + acc[5]) * b2f(t[5]));
    r[6] = f2b((x1.z + y1.z + acc[6]) * b2f(t[6]));
    r[7] = f2b((x1.w + y1.w + acc[7]) * b2f(t[7]));
    *(uint4*)&dst[base] = *(uint4*)r;
}

extern "C" void kernel_launch(void* const* d_in, const int* in_sizes, int n_in,
                              void* d_out, int out_size, void* d_ws, size_t ws_size,
                              hipStream_t stream) {
    const float* x       = (const float*)d_in[0];
    const float* eca_w   = (const float*)d_in[1];
    const float* esa_al  = (const float*)d_in[2];
    const float* cpe1_w  = (const float*)d_in[3];  const float* cpe1_b = (const float*)d_in[4];
    const float* g1      = (const float*)d_in[5];  const float* b1     = (const float*)d_in[6];
    const float* actp_w  = (const float*)d_in[7];  const float* actp_b = (const float*)d_in[8];
    const float* inp_w   = (const float*)d_in[9];  const float* inp_b  = (const float*)d_in[10];
    const float* dwc_w   = (const float*)d_in[11]; const float* dwc_b  = (const float*)d_in[12];
    const float* qkv_w   = (const float*)d_in[13]; const float* qkv_b  = (const float*)d_in[14];
    const float* eaax_w  = (const float*)d_in[15]; const float* eaax_b = (const float*)d_in[16];
    const float* eaay_w  = (const float*)d_in[17]; const float* eaay_b = (const float*)d_in[18];
    const float* outp_w  = (const float*)d_in[19]; const float* outp_b = (const float*)d_in[20];
    const float* cpe2_w  = (const float*)d_in[21]; const float* cpe2_b = (const float*)d_in[22];
    const float* g2      = (const float*)d_in[23]; const float* b2     = (const float*)d_in[24];
    const float* mlp1_w  = (const float*)d_in[25]; const float* mlp1_b = (const float*)d_in[26];
    const float* mlp2_w  = (const float*)d_in[27]; const float* mlp2_b = (const float*)d_in[28];

    float* ws = (float*)d_ws;
    unsigned short* U = (unsigned short*)d_ws;
    const size_t E = (size_t)BATCH * CDIM * NPIX;  // 4,194,304

    float* y_nhwc  = ws;                // [0,E)  esa out; later a0
    float* a0      = ws;
    float* sc_nhwc = ws + E;            // [E,2E) shortcut (live to outp)
    unsigned short* act_t = U + 5 * E;  // [2.5E,3E)
    unsigned short* it_t  = U + 6 * E;  // [3E,3.5E)
    unsigned short* tin_t = U + 7 * E;  // [3.5E,4E)
    float* a1      = ws + 4 * E;        // [4E,5E)
    unsigned short* t_t   = U + 10 * E; // [5E,7.5E)
    unsigned short* m_t   = U + 15 * E; // [7.5E,8E)
    float* out_nhwc = ws + 8 * E;       // [8E,9E)
    float* out2    = ws + 2 * E;        // [2E,3E)  (act_t dead by then)
    unsigned short* hid_t = U + 10 * E; // [5E,7E)  (t_t dead after mul3_cpe)
    unsigned short* wpool = U + 20 * E; // 262144 bf16
    unsigned short* wq  = wpool;
    unsigned short* wm1 = wpool + 81920;
    unsigned short* wm2 = wpool + 147456;
    unsigned short* wai = wpool + 212992;   // actp rows 0-127, inp rows 128-255 (contiguous)
    unsigned short* wo  = wpool + 245760;
    float* fb     = ws + 10 * E + 131072;
    float* meanb  = fb;            // 1024
    float* gstats = fb + 2048;     // 2048: gn1 [0,1024), gn2 [1024,2048)
    float* qb_r   = fb + 4096;     // 640
    float* wsT    = fb + 4736;     // 1152
    float* bsum   = fb + 5888;     // 128
    float* cpe1T  = fb + 6016;     // 1152
    float* dwcT   = fb + 7168;     // 1152
    float* cpe2T  = fb + 8320;     // 1152
    float* abi    = fb + 9472;     // 256

    convert_w_kernel<<<1054, 256, 0, stream>>>(qkv_w, mlp1_w, mlp2_w, actp_w, inp_w, outp_w,
                                               qkv_b, eaax_w, eaax_b, eaay_w, eaay_b,
                                               cpe1_w, dwc_w, cpe2_w, actp_b, inp_b,
                                               wpool, qb_r, wsT, bsum, cpe1T, dwcT, cpe2T, abi,
                                               gstats);

    // 1) ECA + ESA (gate inline) with transpose -> y (f32 NHWC)
    mean_bc_kernel<<<BATCH * CDIM, 256, 0, stream>>>(x, meanb);
    esa_tr_kernel<<<dim3(64, BATCH), 256, 0, stream>>>(x, meanb, eca_w, esa_al, y_nhwc);
    // 2) shortcut = y + cpe1(y), fused GN1 stats
    cpe_f32_kernel<<<dim3(256, BATCH), 256, 0, stream>>>(y_nhwc, cpe1T, cpe1_b, sc_nhwc, gstats);
    // 3+4+5a) merged actp+inp conv with fused GN1 apply: sc_nhwc -> act_t (relu), it_t
    conv_mfma_kernel<<<dim3(64, 1, BATCH), 256, 0, stream>>>(nullptr, sc_nhwc, gstats, g1, b1,
                                                             wai, abi, nullptr, nullptr,
                                                             act_t, it_t, 128, 128, 2, 0, 2);
    // 5b) tin = relu(dwc(it))
    dwc_bf16_kernel<<<dim3(256, BATCH), 256, 0, stream>>>(it_t, dwcT, dwc_b, tin_t);
    // 6) qkv -> t_t (bf16 NHWC, 640 grouped; q groups pre-scaled by log2e)
    conv_mfma_kernel<<<dim3(64, 1, BATCH), 256, 0, stream>>>(tin_t, nullptr, nullptr, nullptr,
                                                             nullptr, wq, qb_r, nullptr, nullptr,
                                                             t_t, nullptr, 128, 640, 0, 0, 5);
    // 7) both attentions -> a0, a1
    attn_dual_kernel<<<dim3(16, 8, 2 * BATCH), 256, 0, stream>>>(t_t, a0, a1);
    // 8) m_t = bf16((a0+a1+cpe(v0))*act) ; out = outp(m) + shortcut -> out_nhwc
    mul3_cpe_kernel<<<dim3(256, BATCH), 256, 0, stream>>>(a0, a1, act_t, t_t, wsT, bsum, m_t);
    conv_mfma_kernel<<<dim3(64, 1, BATCH), 256, 0, stream>>>(m_t, nullptr, nullptr, nullptr,
                                                             nullptr, wo, outp_b, sc_nhwc,
                                                             out_nhwc, nullptr, nullptr,
                                                             128, 128, 0, 0, 1);
    // 9) out2 = out + cpe2(out), fused GN2 stats
    cpe_f32_kernel<<<dim3(256, BATCH), 256, 0, stream>>>(out_nhwc, cpe2T, cpe2_b, out2,
                                                         gstats + 1024);
    // 10+11) mlp1 with fused GN2 apply -> hid_t ; mlp2 + out2 residual -> d_out (NCHW)
    conv_mfma_kernel<<<dim3(64, 1, BATCH), 256, 0, stream>>>(nullptr, out2, gstats + 1024, g2, b2,
                                                             wm1, mlp1_b, nullptr, nullptr,
                                                             hid_t, nullptr, 128, 512, 1, 0, 4);
    conv_mfma_kernel<<<dim3(64, 1, BATCH), 256, 0, stream>>>(hid_t, nullptr, nullptr, nullptr,
                                                             nullptr, wm2, mlp2_b, out2,
                                                             (float*)d_out, nullptr, nullptr,
                                                             512, 128, 0, 1, 1);
}

// Round 3
// 297.117 us; speedup vs baseline: 1.0861x; 1.0861x over previous
//
#include <hip/hip_runtime.h>

#define NPIX 4096
#define CDIM 128
#define BATCH 8
#define EPSN 1e-5f
#define LOG2E 1.44269504088896340736f

typedef __attribute__((ext_vector_type(8))) short short8;
typedef __attribute__((ext_vector_type(4))) float f32x4;
typedef __attribute__((ext_vector_type(16))) float f32x16;

__device__ __forceinline__ float sigmoidf_(float x) { return 1.f / (1.f + __expf(-x)); }

__device__ __forceinline__ unsigned short f2b(float f) {
    unsigned int u = __float_as_uint(f);
    unsigned int r = (u + 0x7FFF + ((u >> 16) & 1)) >> 16;  // RNE
    return (unsigned short)r;
}
__device__ __forceinline__ float b2f(unsigned short u) {
    return __uint_as_float((unsigned int)u << 16);
}

// exchange: after call, a = {a.lo, b.lo->hi}, b = {a.hi->lo, b.hi}
// (v_permlane32_swap_b32 swaps upper 32 lanes of a with lower 32 lanes of b)
__device__ __forceinline__ void pl32swap(unsigned int& a, unsigned int& b) {
    asm("v_permlane32_swap_b32 %0, %1" : "+v"(a), "+v"(b));
}

// window token -> pixel index
__device__ __forceinline__ int tok2pix(int mode, int wi, int l) {
    return (mode == 0) ? ((l >> 2) * 64 + wi * 4 + (l & 3))
                       : ((wi * 4 + (l >> 6)) * 64 + (l & 63));
}

// ---------------- weight conversion / reorder / transposes / gstats zeroing ----------------
// q0/q1 weight+bias groups pre-scaled by log2(e) so attention can use native exp2.
__global__ __launch_bounds__(256) void convert_w_kernel(const float* __restrict__ qkv_w,
                                                        const float* __restrict__ mlp1_w,
                                                        const float* __restrict__ mlp2_w,
                                                        const float* __restrict__ actp_w,
                                                        const float* __restrict__ inp_w,
                                                        const float* __restrict__ outp_w,
                                                        const float* __restrict__ qkv_b,
                                                        const float* __restrict__ eaax_w,
                                                        const float* __restrict__ eaax_b,
                                                        const float* __restrict__ eaay_w,
                                                        const float* __restrict__ eaay_b,
                                                        const float* __restrict__ cpe1_w,
                                                        const float* __restrict__ dwc_w,
                                                        const float* __restrict__ cpe2_w,
                                                        const float* __restrict__ actp_b,
                                                        const float* __restrict__ inp_b,
                                                        unsigned short* __restrict__ dst,
                                                        float* __restrict__ qb_r,
                                                        float* __restrict__ wsT,
                                                        float* __restrict__ bsum,
                                                        float* __restrict__ cpe1T,
                                                        float* __restrict__ dwcT,
                                                        float* __restrict__ cpe2T,
                                                        float* __restrict__ abi,
                                                        float* __restrict__ gstats) {
    int i = blockIdx.x * 256 + threadIdx.x;
    if (i >= 267776) {
        if (i < 269824) gstats[i - 267776] = 0.f;
        return;
    }
    if (i < 262144) {
        float v;
        if (i < 81920) {
            int o = i >> 7, c = i & 127;              // reordered: o_new = g*128+cc
            int g = o >> 7;
            v = qkv_w[(size_t)(5 * (o & 127) + g) * 128 + c];
            if (g == 0 || g == 3) v *= LOG2E;         // q0/q1 pre-scale for exp2
        } else if (i < 147456) v = mlp1_w[i - 81920];
        else if (i < 212992)   v = mlp2_w[i - 147456];
        else if (i < 229376)   v = actp_w[i - 212992];
        else if (i < 245760)   v = inp_w[i - 229376];
        else                   v = outp_w[i - 245760];
        dst[i] = f2b(v);
    } else {
        int j = i - 262144;
        if (j < 640) {
            int g = j >> 7;
            float v = qkv_b[5 * (j & 127) + g];
            if (g == 0 || g == 3) v *= LOG2E;
            qb_r[j] = v;
        }
        else if (j < 1792) {
            int idx = j - 640; int k = idx >> 7, c = idx & 127;
            wsT[idx] = eaax_w[c * 9 + k] + eaay_w[c * 9 + k];
        } else if (j < 1920) bsum[j - 1792] = eaax_b[j - 1792] + eaay_b[j - 1792];
        else if (j < 3072) {
            int idx = j - 1920; int k = idx >> 7, c = idx & 127;
            cpe1T[idx] = cpe1_w[c * 9 + k];
        } else if (j < 4224) {
            int idx = j - 3072; int k = idx >> 7, c = idx & 127;
            dwcT[idx] = dwc_w[c * 9 + k];
        } else if (j < 5376) {
            int idx = j - 4224; int k = idx >> 7, c = idx & 127;
            cpe2T[idx] = cpe2_w[c * 9 + k];
        } else {
            int idx = j - 5376;
            abi[idx] = (idx < 128) ? actp_b[idx] : inp_b[idx - 128];
        }
    }
}

// ---------------- per-(b,c) mean over HW (x is NCHW input) ----------------
__global__ __launch_bounds__(256) void mean_bc_kernel(const float* __restrict__ x,
                                                      float* __restrict__ mean) {
    __shared__ float sb[4];
    int bc = blockIdx.x;
    const float* p = x + (size_t)bc * NPIX;
    float s = 0.f;
    for (int i = threadIdx.x; i < NPIX; i += 256) s += p[i];
#pragma unroll
    for (int off = 32; off > 0; off >>= 1) s += __shfl_down(s, off, 64);
    if ((threadIdx.x & 63) == 0) sb[threadIdx.x >> 6] = s;
    __syncthreads();
    if (threadIdx.x == 0) mean[bc] = (sb[0] + sb[1] + sb[2] + sb[3]) * (1.f / (float)NPIX);
}

// ---------------- ESA+ECA fused (gate computed inline) with NCHW->NHWC transpose ----------------
__global__ __launch_bounds__(256) void esa_tr_kernel(const float* __restrict__ x,
                                                     const float* __restrict__ mean,
                                                     const float* __restrict__ w5,
                                                     const float* __restrict__ alpha_p,
                                                     float* __restrict__ y) {
    __shared__ float tile[128][65];
    __shared__ float smx[4][64], smn[4][64], ssc[64], gat[128];
    int b = blockIdx.y, p0 = blockIdx.x * 64;
    int tx = threadIdx.x, pl = tx & 63, part = tx >> 6;
    const float* xb = x + (size_t)b * CDIM * NPIX;
    const float* mb = mean + b * CDIM;
    for (int c = part; c < CDIM; c += 4)
        tile[c][pl] = xb[(size_t)c * NPIX + p0 + pl];
    __syncthreads();
    float mx = -1e30f, mn = 1e30f;
#pragma unroll
    for (int cc = 0; cc < 32; ++cc) {
        int c = part * 32 + cc;
        float v = tile[c][pl] - mb[c];
        mx = fmaxf(mx, v); mn = fminf(mn, v);
    }
    smx[part][pl] = mx; smn[part][pl] = mn;
    __syncthreads();
    if (tx < 128) {
        float s = 0.f;
#pragma unroll
        for (int k = 0; k < 5; ++k) {
            int cc = tx + k - 2;
            if (cc >= 0 && cc < CDIM) s += w5[k] * mb[cc];
        }
        gat[tx] = sigmoidf_(s);
    }
    if (part == 0) {
        float m1 = fmaxf(fmaxf(smx[0][pl], smx[1][pl]), fmaxf(smx[2][pl], smx[3][pl]));
        float m2 = fminf(fminf(smn[0][pl], smn[1][pl]), fminf(smn[2][pl], smn[3][pl]));
        float a = alpha_p[0];
        ssc[pl] = sigmoidf_(m1) * a + sigmoidf_(m2) * (1.f - a);
    }
    __syncthreads();
    int c2 = tx & 127, pr = tx >> 7;
    float* yb = y + ((size_t)b * NPIX + p0) * CDIM;
    float gv = gat[c2];
    for (int p = pr; p < 64; p += 2)
        yb[(size_t)p * CDIM + c2] = tile[c2][p] * (gv + ssc[p]);
}

// ---------------- NHWC f32 dwconv3 + residual + fused PER-BATCH GN stats (8 spread slots) ----------------
__global__ __launch_bounds__(256) void cpe_f32_kernel(const float* __restrict__ in,
                                                      const float* __restrict__ wT,
                                                      const float* __restrict__ bias,
                                                      float* __restrict__ out,
                                                      float* __restrict__ stats) {
    __shared__ float sb[8];
    int b = blockIdx.y, tx = threadIdx.x;
    int cg = tx & 15, pp = tx >> 4;
    int p = blockIdx.x * 16 + pp;
    int xx = p & 63, yy = p >> 6;
    int c0 = cg * 8;
    float acc[8], ctr[8];
#pragma unroll
    for (int j = 0; j < 8; ++j) acc[j] = bias[c0 + j];
#pragma unroll
    for (int dy = -1; dy <= 1; ++dy) {
        int y2 = yy + dy;
        if (y2 < 0 || y2 >= 64) continue;
#pragma unroll
        for (int dx = -1; dx <= 1; ++dx) {
            int x2 = xx + dx;
            if (x2 < 0 || x2 >= 64) continue;
            const float* ip = &in[((size_t)b * NPIX + y2 * 64 + x2) * 128 + c0];
            float4 v0 = *(const float4*)ip;
            float4 v1 = *(const float4*)(ip + 4);
            const float* wr = wT + ((dy + 1) * 3 + dx + 1) * 128 + c0;
            acc[0] += v0.x * wr[0]; acc[1] += v0.y * wr[1];
            acc[2] += v0.z * wr[2]; acc[3] += v0.w * wr[3];
            acc[4] += v1.x * wr[4]; acc[5] += v1.y * wr[5];
            acc[6] += v1.z * wr[6]; acc[7] += v1.w * wr[7];
            if (dy == 0 && dx == 0) {
                ctr[0] = v0.x; ctr[1] = v0.y; ctr[2] = v0.z; ctr[3] = v0.w;
                ctr[4] = v1.x; ctr[5] = v1.y; ctr[6] = v1.z; ctr[7] = v1.w;
            }
        }
    }
    float s = 0.f, s2 = 0.f;
    float r[8];
#pragma unroll
    for (int j = 0; j < 8; ++j) {
        r[j] = ctr[j] + acc[j];
        s += r[j]; s2 += r[j] * r[j];
    }
    float* op = &out[((size_t)b * NPIX + p) * 128 + c0];
    *(float4*)op = make_float4(r[0], r[1], r[2], r[3]);
    *(float4*)(op + 4) = make_float4(r[4], r[5], r[6], r[7]);
#pragma unroll
    for (int off = 32; off > 0; off >>= 1) {
        s += __shfl_down(s, off, 64);
        s2 += __shfl_down(s2, off, 64);
    }
    int wv = tx >> 6;
    if ((tx & 63) == 0) { sb[wv] = s; sb[4 + wv] = s2; }
    __syncthreads();
    if (tx == 0) {
        int slot = (b * 8 + (blockIdx.x & 7)) * 16;
        atomicAdd(&stats[slot], sb[0] + sb[1] + sb[2] + sb[3]);
        atomicAdd(&stats[slot + 1], sb[4] + sb[5] + sb[6] + sb[7]);
    }
}

// ---------------- NHWC bf16 dwconv3 + bias + relu -> bf16 ----------------
__global__ __launch_bounds__(256) void dwc_bf16_kernel(const unsigned short* __restrict__ in,
                                                       const float* __restrict__ wT,
                                                       const float* __restrict__ bias,
                                                       unsigned short* __restrict__ out) {
    int b = blockIdx.y, tx = threadIdx.x;
    int cg = tx & 15, pp = tx >> 4;
    int p = blockIdx.x * 16 + pp;
    int xx = p & 63, yy = p >> 6;
    int c0 = cg * 8;
    float acc[8];
#pragma unroll
    for (int j = 0; j < 8; ++j) acc[j] = bias[c0 + j];
#pragma unroll
    for (int dy = -1; dy <= 1; ++dy) {
        int y2 = yy + dy;
        if (y2 < 0 || y2 >= 64) continue;
#pragma unroll
        for (int dx = -1; dx <= 1; ++dx) {
            int x2 = xx + dx;
            if (x2 < 0 || x2 >= 64) continue;
            unsigned short v[8];
            *(uint4*)v = *(const uint4*)&in[((size_t)b * NPIX + y2 * 64 + x2) * 128 + c0];
            const float* wr = wT + ((dy + 1) * 3 + dx + 1) * 128 + c0;
#pragma unroll
            for (int j = 0; j < 8; ++j) acc[j] += b2f(v[j]) * wr[j];
        }
    }
    unsigned short o[8];
#pragma unroll
    for (int j = 0; j < 8; ++j) o[j] = f2b(fmaxf(acc[j], 0.f));
    *(uint4*)&out[((size_t)b * NPIX + p) * 128 + c0] = *(uint4*)o;
}

// ---------------- conv1x1 via bf16 MFMA, 128out x 64px tile (round-1 y-parallel form) ----------------
__global__ __launch_bounds__(256) void conv_mfma_kernel(const unsigned short* __restrict__ in_t,
                                                        const float* __restrict__ in_f32,
                                                        const float* __restrict__ gst,
                                                        const float* __restrict__ gg,
                                                        const float* __restrict__ gbta,
                                                        const unsigned short* __restrict__ w,
                                                        const float* __restrict__ bias,
                                                        const float* __restrict__ res,
                                                        float* __restrict__ out,
                                                        unsigned short* __restrict__ out_t,
                                                        unsigned short* __restrict__ out_t2,
                                                        int Cin, int Cout, int relu, int nchw) {
    __shared__ __align__(16) unsigned short A_s[128][136];
    __shared__ __align__(16) unsigned short B_s[64][136];
    int b = blockIdx.z, p0 = blockIdx.x * 64, o0 = blockIdx.y * 128;
    int tx = threadIdx.x;
    int wave = tx >> 6, lane = tx & 63;
    int wm = wave & 1, wn = wave >> 1;
    int quad = lane >> 4, l16 = lane & 15;

    float mu = 0.f, rr = 1.f;
    if (in_f32) {
        float su = 0.f, sq = 0.f;
#pragma unroll
        for (int sl = 0; sl < 8; ++sl) {
            su += gst[(b * 8 + sl) * 16];
            sq += gst[(b * 8 + sl) * 16 + 1];
        }
        const float n = 1.f / (float)(CDIM * NPIX);
        mu = su * n;
        float var = sq * n - mu * mu;
        rr = rsqrtf(var + EPSN);
    }

    f32x4 acc[4][2];
#pragma unroll
    for (int mt = 0; mt < 4; ++mt) {
#pragma unroll
        for (int r = 0; r < 4; ++r) {
            float bv = bias[o0 + wm * 64 + mt * 16 + quad * 4 + r];
#pragma unroll
            for (int nt = 0; nt < 2; ++nt) acc[mt][nt][r] = bv;
        }
    }

    for (int k0 = 0; k0 < Cin; k0 += 128) {
#pragma unroll
        for (int j = 0; j < 8; ++j) {
            int idx = tx + 256 * j;
            int row = idx >> 4, c16 = idx & 15;
            *(uint4*)&A_s[row][c16 * 8] =
                *(const uint4*)&w[(size_t)(o0 + row) * Cin + k0 + c16 * 8];
        }
        if (in_f32) {
#pragma unroll
            for (int j = 0; j < 4; ++j) {
                int idx = tx + 256 * j;
                int row = idx >> 4, c16 = idx & 15;
                int ch = c16 * 8;  // Cin==128
                const float* ip = &in_f32[((size_t)b * NPIX + p0 + row) * 128 + ch];
                float4 v0 = *(const float4*)ip;
                float4 v1 = *(const float4*)(ip + 4);
                unsigned short o[8];
                o[0] = f2b((v0.x - mu) * rr * gg[ch + 0] + gbta[ch + 0]);
                o[1] = f2b((v0.y - mu) * rr * gg[ch + 1] + gbta[ch + 1]);
                o[2] = f2b((v0.z - mu) * rr * gg[ch + 2] + gbta[ch + 2]);
                o[3] = f2b((v0.w - mu) * rr * gg[ch + 3] + gbta[ch + 3]);
                o[4] = f2b((v1.x - mu) * rr * gg[ch + 4] + gbta[ch + 4]);
                o[5] = f2b((v1.y - mu) * rr * gg[ch + 5] + gbta[ch + 5]);
                o[6] = f2b((v1.z - mu) * rr * gg[ch + 6] + gbta[ch + 6]);
                o[7] = f2b((v1.w - mu) * rr * gg[ch + 7] + gbta[ch + 7]);
                *(uint4*)&B_s[row][c16 * 8] = *(uint4*)o;
            }
        } else {
#pragma unroll
            for (int j = 0; j < 4; ++j) {
                int idx = tx + 256 * j;
                int row = idx >> 4, c16 = idx & 15;
                *(uint4*)&B_s[row][c16 * 8] =
                    *(const uint4*)&in_t[((size_t)b * NPIX + p0 + row) * Cin + k0 + c16 * 8];
            }
        }
        __syncthreads();
#pragma unroll
        for (int ks = 0; ks < 128; ks += 32) {
            short8 af[4], bf[2];
#pragma unroll
            for (int mt = 0; mt < 4; ++mt)
                af[mt] = *(const short8*)&A_s[wm * 64 + mt * 16 + l16][ks + quad * 8];
#pragma unroll
            for (int nt = 0; nt < 2; ++nt)
                bf[nt] = *(const short8*)&B_s[wn * 32 + nt * 16 + l16][ks + quad * 8];
#pragma unroll
            for (int mt = 0; mt < 4; ++mt)
#pragma unroll
                for (int nt = 0; nt < 2; ++nt)
                    acc[mt][nt] = __builtin_amdgcn_mfma_f32_16x16x32_bf16(
                        af[mt], bf[nt], acc[mt][nt], 0, 0, 0);
        }
        __syncthreads();
    }

    int dorelu = (relu == 1) || (relu == 2 && blockIdx.y == 0);
    if (out_t) {
#pragma unroll
        for (int mt = 0; mt < 4; ++mt) {
#pragma unroll
            for (int nt = 0; nt < 2; ++nt) {
                int p = p0 + wn * 32 + nt * 16 + l16;
                int ob = o0 + wm * 64 + mt * 16 + quad * 4;
                unsigned short* dbuf = out_t;
                int oc = ob;
                if (out_t2 && o0 >= 128) { dbuf = out_t2; oc = ob - 128; }
                ushort4 u;
                float v0 = acc[mt][nt][0], v1 = acc[mt][nt][1];
                float v2 = acc[mt][nt][2], v3 = acc[mt][nt][3];
                if (dorelu) { v0 = fmaxf(v0, 0.f); v1 = fmaxf(v1, 0.f);
                              v2 = fmaxf(v2, 0.f); v3 = fmaxf(v3, 0.f); }
                u.x = f2b(v0); u.y = f2b(v1); u.z = f2b(v2); u.w = f2b(v3);
                *(ushort4*)&dbuf[((size_t)b * NPIX + p) * Cout + oc] = u;
            }
        }
    } else if (!nchw) {
#pragma unroll
        for (int mt = 0; mt < 4; ++mt) {
#pragma unroll
            for (int nt = 0; nt < 2; ++nt) {
                int p = p0 + wn * 32 + nt * 16 + l16;
                int ob = o0 + wm * 64 + mt * 16 + quad * 4;
                size_t ix = ((size_t)b * NPIX + p) * Cout + ob;
                float4 v = make_float4(acc[mt][nt][0], acc[mt][nt][1],
                                       acc[mt][nt][2], acc[mt][nt][3]);
                if (dorelu) { v.x = fmaxf(v.x, 0.f); v.y = fmaxf(v.y, 0.f);
                              v.z = fmaxf(v.z, 0.f); v.w = fmaxf(v.w, 0.f); }
                if (res) {
                    float4 rv = *(const float4*)&res[ix];
                    v.x += rv.x; v.y += rv.y; v.z += rv.z; v.w += rv.w;
                }
                *(float4*)&out[ix] = v;
            }
        }
    } else {
        float* outb = out + (size_t)b * Cout * NPIX;
#pragma unroll
        for (int mt = 0; mt < 4; ++mt) {
#pragma unroll
            for (int nt = 0; nt < 2; ++nt) {
                int p = p0 + wn * 32 + nt * 16 + l16;
                int ob = o0 + wm * 64 + mt * 16 + quad * 4;
                float4 rv = make_float4(0.f, 0.f, 0.f, 0.f);
                if (res) rv = *(const float4*)&res[((size_t)b * NPIX + p) * 128 + ob];
#pragma unroll
                for (int r = 0; r < 4; ++r) {
                    float v = acc[mt][nt][r];
                    if (dorelu) v = fmaxf(v, 0.f);
                    v += (r == 0 ? rv.x : r == 1 ? rv.y : r == 2 ? rv.z : rv.w);
                    outb[(size_t)(ob + r) * NPIX + p] = v;
                }
            }
        }
    }
}

// ---------------- MFMA window attention, both orientations in one launch ----------------
// q pre-scaled by log2(e) -> native exp2; row-sum via ones-row at PV A row 16 (o_acc[8]).
// LOOP ORDER: nt outer, both q-slices inner — each scattered kf load and each V ds_read
// pair is issued ONCE and consumed by both q accumulators (was loaded twice with qi outer;
// scattered 1280B-stride gathers are the latency bottleneck, VALUBusy 36% / MfmaUtil 11%).
// P-fragment redistribution via v_permlane32_swap_b32; V tile padded to 32 rows
// (row16=ones for row-sum, 17-31=0) so PV A-operand reads are unconditional.
__global__ __launch_bounds__(256) void attn_dual_kernel(const unsigned short* __restrict__ t_t,
                                                        float* __restrict__ a0,
                                                        float* __restrict__ a1) {
    __shared__ __align__(16) unsigned short Vt[32][264];
    int wi = blockIdx.x, head = blockIdx.y;
    int z = blockIdx.z;
    int b = z >> 1, which = z & 1;
    int qoff = which ? 384 : 0;
    int koff = which ? 512 : 128;
    int mode = which;
    float* a_out = which ? a1 : a0;
    int tx = threadIdx.x;
    int wave = tx >> 6, l = tx & 63;
    int l32 = l & 31, half = l >> 5;
    const size_t base = (size_t)b * NPIX;
    const int hc = head * 16;

    {
        int p = tok2pix(mode, wi, tx);
        const unsigned short* vp = &t_t[(base + p) * 640 + 256 + hc];
        unsigned short tmp[16];
        *(uint4*)&tmp[0] = *(const uint4*)vp;
        *(uint4*)&tmp[8] = *(const uint4*)(vp + 8);
#pragma unroll
        for (int d = 0; d < 16; ++d) Vt[d][tx] = tmp[d];
        Vt[16][tx] = (unsigned short)0x3F80;  // bf16 1.0 — row-sum row
#pragma unroll
        for (int d = 17; d < 32; ++d) Vt[d][tx] = 0;
    }
    __syncthreads();

    f32x16 zzero;
#pragma unroll
    for (int r = 0; r < 16; ++r) zzero[r] = 0.f;

    // per-lane pixel offsets (in ushort units) for the 8 token chunks
    int pofs[8];
#pragma unroll
    for (int nt = 0; nt < 8; ++nt)
        pofs[nt] = tok2pix(mode, wi, nt * 32 + l32) * 640;

    const unsigned short* tb = t_t + base * 640 + hc + half * 8;
    const unsigned short* kb = tb + koff;
    const unsigned short* qb = tb + qoff;

    int qp0 = tok2pix(mode, wi, (0 * 4 + wave) * 32 + l32);
    int qp1 = tok2pix(mode, wi, (1 * 4 + wave) * 32 + l32);
    short8 qf0 = *(const short8*)&qb[(size_t)qp0 * 640];
    short8 qf1 = *(const short8*)&qb[(size_t)qp1 * 640];
    f32x16 oa0 = zzero, oa1 = zzero;

#pragma unroll
    for (int nt = 0; nt < 8; ++nt) {
        short8 kf = *(const short8*)&kb[pofs[nt]];
        short8 vf0 = *(const short8*)&Vt[l32][nt * 32 + half * 8];
        short8 vf1 = *(const short8*)&Vt[l32][nt * 32 + 16 + half * 8];
#pragma unroll
        for (int qi = 0; qi < 2; ++qi) {
            short8 qf = (qi == 0) ? qf0 : qf1;
            f32x16 s = __builtin_amdgcn_mfma_f32_32x32x16_bf16(kf, qf, zzero, 0, 0, 0);
            unsigned int pk[8];
#pragma unroll
            for (int i = 0; i < 8; ++i) {
                float e0 = __builtin_amdgcn_exp2f(s[2 * i]);
                float e1 = __builtin_amdgcn_exp2f(s[2 * i + 1]);
                pk[i] = __builtin_amdgcn_perm(__float_as_uint(e1), __float_as_uint(e0),
                                              0x07060302u);
            }
            // redistribute halves: (u0[0],u0[2]) = swap(pk0,pk2), etc.
            pl32swap(pk[0], pk[2]);
            pl32swap(pk[1], pk[3]);
            pl32swap(pk[4], pk[6]);
            pl32swap(pk[5], pk[7]);
            unsigned int u0[4] = {pk[0], pk[1], pk[2], pk[3]};
            unsigned int u1[4] = {pk[4], pk[5], pk[6], pk[7]};
            if (qi == 0) {
                oa0 = __builtin_amdgcn_mfma_f32_32x32x16_bf16(vf0, *(short8*)u0, oa0, 0, 0, 0);
                oa0 = __builtin_amdgcn_mfma_f32_32x32x16_bf16(vf1, *(short8*)u1, oa0, 0, 0, 0);
            } else {
                oa1 = __builtin_amdgcn_mfma_f32_32x32x16_bf16(vf0, *(short8*)u0, oa1, 0, 0, 0);
                oa1 = __builtin_amdgcn_mfma_f32_32x32x16_bf16(vf1, *(short8*)u1, oa1, 0, 0, 0);
            }
        }
    }

    // epilogue for both q-slices: row 16 of PV output = sum_t P[t][col] (r=8)
#pragma unroll
    for (int qi = 0; qi < 2; ++qi) {
        f32x16 oc = (qi == 0) ? oa0 : oa1;
        int qp = (qi == 0) ? qp0 : qp1;
        float rs = oc[8];
        rs += __shfl_xor(rs, 32, 64);
        float rinv = 1.f / rs;
        // d = (r&3) + 8*(r>>2) + 4*half  ->  two contiguous float4 runs
        float* dst = a_out + (base + qp) * 128 + hc + 4 * half;
        float4 s0 = make_float4(oc[0] * rinv, oc[1] * rinv,
                                oc[2] * rinv, oc[3] * rinv);
        float4 s1 = make_float4(oc[4] * rinv, oc[5] * rinv,
                                oc[6] * rinv, oc[7] * rinv);
        *(float4*)dst = s0;
        *(float4*)(dst + 8) = s1;
    }
}

// ---------------- m_t = bf16((a0 + a1 + cpe(v0)) * act_res)  (all NHWC) ----------------
__global__ __launch_bounds__(256) void mul3_cpe_kernel(const float* __restrict__ a0,
                                                       const float* __restrict__ a1,
                                                       const unsigned short* __restrict__ act,
                                                       const unsigned short* __restrict__ t_t,
                                                       const float* __restrict__ wT,
                                                       const float* __restrict__ bsum,
                                                       unsigned short* __restrict__ dst) {
    int b = blockIdx.y;
    int tx = threadIdx.x;
    int cg = tx & 15, pp = tx >> 4;
    int p = blockIdx.x * 16 + pp;
    int xx = p & 63, yy = p >> 6;
    int c0 = cg * 8;
    float acc[8];
#pragma unroll
    for (int j = 0; j < 8; ++j) acc[j] = bsum[c0 + j];
#pragma unroll
    for (int dy = -1; dy <= 1; ++dy) {
        int y2 = yy + dy;
        if (y2 < 0 || y2 >= 64) continue;
#pragma unroll
        for (int dx = -1; dx <= 1; ++dx) {
            int x2 = xx + dx;
            if (x2 < 0 || x2 >= 64) continue;
            int pn = y2 * 64 + x2;
            unsigned short v[8];
            *(uint4*)v = *(const uint4*)&t_t[((size_t)b * NPIX + pn) * 640 + 256 + c0];
            const float* wr = wT + ((dy + 1) * 3 + dx + 1) * 128 + c0;
#pragma unroll
            for (int j = 0; j < 8; ++j) acc[j] += b2f(v[j]) * wr[j];
        }
    }
    size_t base = ((size_t)b * NPIX + p) * 128 + c0;
    float4 x0 = *(const float4*)&a0[base];
    float4 x1 = *(const float4*)&a0[base + 4];
    float4 y0 = *(const float4*)&a1[base];
    float4 y1 = *(const float4*)&a1[base + 4];
    unsigned short t[8];
    *(uint4*)t = *(const uint4*)&act[base];
    unsigned short r[8];
    r[0] = f2b((x0.x + y0.x + acc[0]) * b2f(t[0]));
    r[1] = f2b((x0.y + y0.y + acc[1]) * b2f(t[1]));
    r[2] = f2b((x0.z + y0.z + acc[2]) * b2f(t[2]));
    r[3] = f2b((x0.w + y0.w + acc[3]) * b2f(t[3]));
    r[4] = f2b((x1.x + y1.x + acc[4]) * b2f(t[4]));
    r[5] = f2b((x1.y + y1.y + acc[5]) * b2f(t[5]));
    r[6] = f2b((x1.z + y1.z + acc[6]) * b2f(t[6]));
    r[7] = f2b((x1.w + y1.w + acc[7]) * b2f(t[7]));
    *(uint4*)&dst[base] = *(uint4*)r;
}

extern "C" void kernel_launch(void* const* d_in, const int* in_sizes, int n_in,
                              void* d_out, int out_size, void* d_ws, size_t ws_size,
                              hipStream_t stream) {
    const float* x       = (const float*)d_in[0];
    const float* eca_w   = (const float*)d_in[1];
    const float* esa_al  = (const float*)d_in[2];
    const float* cpe1_w  = (const float*)d_in[3];  const float* cpe1_b = (const float*)d_in[4];
    const float* g1      = (const float*)d_in[5];  const float* b1     = (const float*)d_in[6];
    const float* actp_w  = (const float*)d_in[7];  const float* actp_b = (const float*)d_in[8];
    const float* inp_w   = (const float*)d_in[9];  const float* inp_b  = (const float*)d_in[10];
    const float* dwc_w   = (const float*)d_in[11]; const float* dwc_b  = (const float*)d_in[12];
    const float* qkv_w   = (const float*)d_in[13]; const float* qkv_b  = (const float*)d_in[14];
    const float* eaax_w  = (const float*)d_in[15]; const float* eaax_b = (const float*)d_in[16];
    const float* eaay_w  = (const float*)d_in[17]; const float* eaay_b = (const float*)d_in[18];
    const float* outp_w  = (const float*)d_in[19]; const float* outp_b = (const float*)d_in[20];
    const float* cpe2_w  = (const float*)d_in[21]; const float* cpe2_b = (const float*)d_in[22];
    const float* g2      = (const float*)d_in[23]; const float* b2     = (const float*)d_in[24];
    const float* mlp1_w  = (const float*)d_in[25]; const float* mlp1_b = (const float*)d_in[26];
    const float* mlp2_w  = (const float*)d_in[27]; const float* mlp2_b = (const float*)d_in[28];

    float* ws = (float*)d_ws;
    unsigned short* U = (unsigned short*)d_ws;
    const size_t E = (size_t)BATCH * CDIM * NPIX;  // 4,194,304

    float* y_nhwc  = ws;                // [0,E)  esa out; later a0
    float* a0      = ws;
    float* sc_nhwc = ws + E;            // [E,2E) shortcut (live to outp)
    unsigned short* act_t = U + 5 * E;  // [2.5E,3E)
    unsigned short* it_t  = U + 6 * E;  // [3E,3.5E)
    unsigned short* tin_t = U + 7 * E;  // [3.5E,4E)
    float* a1      = ws + 4 * E;        // [4E,5E)
    unsigned short* t_t   = U + 10 * E; // [5E,7.5E)
    unsigned short* m_t   = U + 15 * E; // [7.5E,8E)
    float* out_nhwc = ws + 8 * E;       // [8E,9E)
    float* out2    = ws + 2 * E;        // [2E,3E)  (act_t dead by then)
    unsigned short* hid_t = U + 10 * E; // [5E,7E)  (t_t dead after mul3_cpe)
    unsigned short* wpool = U + 20 * E; // 262144 bf16
    unsigned short* wq  = wpool;
    unsigned short* wm1 = wpool + 81920;
    unsigned short* wm2 = wpool + 147456;
    unsigned short* wai = wpool + 212992;   // actp rows 0-127, inp rows 128-255 (contiguous)
    unsigned short* wo  = wpool + 245760;
    float* fb     = ws + 10 * E + 131072;
    float* meanb  = fb;            // 1024
    float* gstats = fb + 2048;     // 2048: gn1 [0,1024), gn2 [1024,2048)
    float* qb_r   = fb + 4096;     // 640
    float* wsT    = fb + 4736;     // 1152
    float* bsum   = fb + 5888;     // 128
    float* cpe1T  = fb + 6016;     // 1152
    float* dwcT   = fb + 7168;     // 1152
    float* cpe2T  = fb + 8320;     // 1152
    float* abi    = fb + 9472;     // 256

    convert_w_kernel<<<1054, 256, 0, stream>>>(qkv_w, mlp1_w, mlp2_w, actp_w, inp_w, outp_w,
                                               qkv_b, eaax_w, eaax_b, eaay_w, eaay_b,
                                               cpe1_w, dwc_w, cpe2_w, actp_b, inp_b,
                                               wpool, qb_r, wsT, bsum, cpe1T, dwcT, cpe2T, abi,
                                               gstats);

    // 1) ECA + ESA (gate inline) with transpose -> y (f32 NHWC)
    mean_bc_kernel<<<BATCH * CDIM, 256, 0, stream>>>(x, meanb);
    esa_tr_kernel<<<dim3(64, BATCH), 256, 0, stream>>>(x, meanb, eca_w, esa_al, y_nhwc);
    // 2) shortcut = y + cpe1(y), fused GN1 stats
    cpe_f32_kernel<<<dim3(256, BATCH), 256, 0, stream>>>(y_nhwc, cpe1T, cpe1_b, sc_nhwc, gstats);
    // 3+4+5a) merged actp+inp conv with fused GN1 apply: sc_nhwc -> act_t (relu), it_t
    conv_mfma_kernel<<<dim3(64, 2, BATCH), 256, 0, stream>>>(nullptr, sc_nhwc, gstats, g1, b1,
                                                             wai, abi, nullptr, nullptr,
                                                             act_t, it_t, 128, 128, 2, 0);
    // 5b) tin = relu(dwc(it))
    dwc_bf16_kernel<<<dim3(256, BATCH), 256, 0, stream>>>(it_t, dwcT, dwc_b, tin_t);
    // 6) qkv -> t_t (bf16 NHWC, 640 grouped; q groups pre-scaled by log2e)
    conv_mfma_kernel<<<dim3(64, 5, BATCH), 256, 0, stream>>>(tin_t, nullptr, nullptr, nullptr,
                                                             nullptr, wq, qb_r, nullptr, nullptr,
                                                             t_t, nullptr, 128, 640, 0, 0);
    // 7) both attentions -> a0, a1
    attn_dual_kernel<<<dim3(16, 8, 2 * BATCH), 256, 0, stream>>>(t_t, a0, a1);
    // 8) m_t = bf16((a0+a1+cpe(v0))*act) ; out = outp(m) + shortcut -> out_nhwc
    mul3_cpe_kernel<<<dim3(256, BATCH), 256, 0, stream>>>(a0, a1, act_t, t_t, wsT, bsum, m_t);
    conv_mfma_kernel<<<dim3(64, 1, BATCH), 256, 0, stream>>>(m_t, nullptr, nullptr, nullptr,
                                                             nullptr, wo, outp_b, sc_nhwc,
                                                             out_nhwc, nullptr, nullptr,
                                                             128, 128, 0, 0);
    // 9) out2 = out + cpe2(out), fused GN2 stats
    cpe_f32_kernel<<<dim3(256, BATCH), 256, 0, stream>>>(out_nhwc, cpe2T, cpe2_b, out2,
                                                         gstats + 1024);
    // 10+11) mlp1 with fused GN2 apply -> hid_t ; mlp2 + out2 residual -> d_out (NCHW)
    conv_mfma_kernel<<<dim3(64, 4, BATCH), 256, 0, stream>>>(nullptr, out2, gstats + 1024, g2, b2,
                                                             wm1, mlp1_b, nullptr, nullptr,
                                                             hid_t, nullptr, 128, 512, 1, 0);
    conv_mfma_kernel<<<dim3(64, 1, BATCH), 256, 0, stream>>>(hid_t, nullptr, nullptr, nullptr,
                                                             nullptr, wm2, mlp2_b, out2,
                                                             (float*)d_out, nullptr, nullptr,
                                                             512, 128, 0, 1);
}

// Round 4
// 292.282 us; speedup vs baseline: 1.1041x; 1.0165x over previous
//
#include <hip/hip_runtime.h>

#define NPIX 4096
#define CDIM 128
#define BATCH 8
#define EPSN 1e-5f
#define LOG2E 1.44269504088896340736f

typedef __attribute__((ext_vector_type(8))) short short8;
typedef __attribute__((ext_vector_type(4))) float f32x4;
typedef __attribute__((ext_vector_type(16))) float f32x16;

__device__ __forceinline__ float sigmoidf_(float x) { return 1.f / (1.f + __expf(-x)); }

__device__ __forceinline__ unsigned short f2b(float f) {
    unsigned int u = __float_as_uint(f);
    unsigned int r = (u + 0x7FFF + ((u >> 16) & 1)) >> 16;  // RNE
    return (unsigned short)r;
}
__device__ __forceinline__ float b2f(unsigned short u) {
    return __uint_as_float((unsigned int)u << 16);
}

// exchange: after call, a = {a.lo, b.lo->hi}, b = {a.hi->lo, b.hi}
// (v_permlane32_swap_b32 swaps upper 32 lanes of a with lower 32 lanes of b)
__device__ __forceinline__ void pl32swap(unsigned int& a, unsigned int& b) {
    asm("v_permlane32_swap_b32 %0, %1" : "+v"(a), "+v"(b));
}

// window token -> pixel index
__device__ __forceinline__ int tok2pix(int mode, int wi, int l) {
    return (mode == 0) ? ((l >> 2) * 64 + wi * 4 + (l & 3))
                       : ((wi * 4 + (l >> 6)) * 64 + (l & 63));
}

// ---------------- weight conversion / reorder / transposes / gstats zeroing ----------------
// q0/q1 weight+bias groups pre-scaled by log2(e) so attention can use native exp2.
__global__ __launch_bounds__(256) void convert_w_kernel(const float* __restrict__ qkv_w,
                                                        const float* __restrict__ mlp1_w,
                                                        const float* __restrict__ mlp2_w,
                                                        const float* __restrict__ actp_w,
                                                        const float* __restrict__ inp_w,
                                                        const float* __restrict__ outp_w,
                                                        const float* __restrict__ qkv_b,
                                                        const float* __restrict__ eaax_w,
                                                        const float* __restrict__ eaax_b,
                                                        const float* __restrict__ eaay_w,
                                                        const float* __restrict__ eaay_b,
                                                        const float* __restrict__ cpe1_w,
                                                        const float* __restrict__ dwc_w,
                                                        const float* __restrict__ cpe2_w,
                                                        const float* __restrict__ actp_b,
                                                        const float* __restrict__ inp_b,
                                                        unsigned short* __restrict__ dst,
                                                        float* __restrict__ qb_r,
                                                        float* __restrict__ wsT,
                                                        float* __restrict__ bsum,
                                                        float* __restrict__ cpe1T,
                                                        float* __restrict__ dwcT,
                                                        float* __restrict__ cpe2T,
                                                        float* __restrict__ abi,
                                                        float* __restrict__ gstats) {
    int i = blockIdx.x * 256 + threadIdx.x;
    if (i >= 267776) {
        if (i < 269824) gstats[i - 267776] = 0.f;
        return;
    }
    if (i < 262144) {
        float v;
        if (i < 81920) {
            int o = i >> 7, c = i & 127;              // reordered: o_new = g*128+cc
            int g = o >> 7;
            v = qkv_w[(size_t)(5 * (o & 127) + g) * 128 + c];
            if (g == 0 || g == 3) v *= LOG2E;         // q0/q1 pre-scale for exp2
        } else if (i < 147456) v = mlp1_w[i - 81920];
        else if (i < 212992)   v = mlp2_w[i - 147456];
        else if (i < 229376)   v = actp_w[i - 212992];
        else if (i < 245760)   v = inp_w[i - 229376];
        else                   v = outp_w[i - 245760];
        dst[i] = f2b(v);
    } else {
        int j = i - 262144;
        if (j < 640) {
            int g = j >> 7;
            float v = qkv_b[5 * (j & 127) + g];
            if (g == 0 || g == 3) v *= LOG2E;
            qb_r[j] = v;
        }
        else if (j < 1792) {
            int idx = j - 640; int k = idx >> 7, c = idx & 127;
            wsT[idx] = eaax_w[c * 9 + k] + eaay_w[c * 9 + k];
        } else if (j < 1920) bsum[j - 1792] = eaax_b[j - 1792] + eaay_b[j - 1792];
        else if (j < 3072) {
            int idx = j - 1920; int k = idx >> 7, c = idx & 127;
            cpe1T[idx] = cpe1_w[c * 9 + k];
        } else if (j < 4224) {
            int idx = j - 3072; int k = idx >> 7, c = idx & 127;
            dwcT[idx] = dwc_w[c * 9 + k];
        } else if (j < 5376) {
            int idx = j - 4224; int k = idx >> 7, c = idx & 127;
            cpe2T[idx] = cpe2_w[c * 9 + k];
        } else {
            int idx = j - 5376;
            abi[idx] = (idx < 128) ? actp_b[idx] : inp_b[idx - 128];
        }
    }
}

// ---------------- per-(b,c) mean over HW (x is NCHW input) ----------------
__global__ __launch_bounds__(256) void mean_bc_kernel(const float* __restrict__ x,
                                                      float* __restrict__ mean) {
    __shared__ float sb[4];
    int bc = blockIdx.x;
    const float* p = x + (size_t)bc * NPIX;
    float s = 0.f;
    for (int i = threadIdx.x; i < NPIX; i += 256) s += p[i];
#pragma unroll
    for (int off = 32; off > 0; off >>= 1) s += __shfl_down(s, off, 64);
    if ((threadIdx.x & 63) == 0) sb[threadIdx.x >> 6] = s;
    __syncthreads();
    if (threadIdx.x == 0) mean[bc] = (sb[0] + sb[1] + sb[2] + sb[3]) * (1.f / (float)NPIX);
}

// ---------------- ESA+ECA fused (gate computed inline) with NCHW->NHWC transpose ----------------
__global__ __launch_bounds__(256) void esa_tr_kernel(const float* __restrict__ x,
                                                     const float* __restrict__ mean,
                                                     const float* __restrict__ w5,
                                                     const float* __restrict__ alpha_p,
                                                     float* __restrict__ y) {
    __shared__ float tile[128][65];
    __shared__ float smx[4][64], smn[4][64], ssc[64], gat[128];
    int b = blockIdx.y, p0 = blockIdx.x * 64;
    int tx = threadIdx.x, pl = tx & 63, part = tx >> 6;
    const float* xb = x + (size_t)b * CDIM * NPIX;
    const float* mb = mean + b * CDIM;
    for (int c = part; c < CDIM; c += 4)
        tile[c][pl] = xb[(size_t)c * NPIX + p0 + pl];
    __syncthreads();
    float mx = -1e30f, mn = 1e30f;
#pragma unroll
    for (int cc = 0; cc < 32; ++cc) {
        int c = part * 32 + cc;
        float v = tile[c][pl] - mb[c];
        mx = fmaxf(mx, v); mn = fminf(mn, v);
    }
    smx[part][pl] = mx; smn[part][pl] = mn;
    __syncthreads();
    if (tx < 128) {
        float s = 0.f;
#pragma unroll
        for (int k = 0; k < 5; ++k) {
            int cc = tx + k - 2;
            if (cc >= 0 && cc < CDIM) s += w5[k] * mb[cc];
        }
        gat[tx] = sigmoidf_(s);
    }
    if (part == 0) {
        float m1 = fmaxf(fmaxf(smx[0][pl], smx[1][pl]), fmaxf(smx[2][pl], smx[3][pl]));
        float m2 = fminf(fminf(smn[0][pl], smn[1][pl]), fminf(smn[2][pl], smn[3][pl]));
        float a = alpha_p[0];
        ssc[pl] = sigmoidf_(m1) * a + sigmoidf_(m2) * (1.f - a);
    }
    __syncthreads();
    int c2 = tx & 127, pr = tx >> 7;
    float* yb = y + ((size_t)b * NPIX + p0) * CDIM;
    float gv = gat[c2];
    for (int p = pr; p < 64; p += 2)
        yb[(size_t)p * CDIM + c2] = tile[c2][p] * (gv + ssc[p]);
}

// ---------------- NHWC f32 dwconv3 + residual + fused PER-BATCH GN stats (8 spread slots) ----------------
__global__ __launch_bounds__(256) void cpe_f32_kernel(const float* __restrict__ in,
                                                      const float* __restrict__ wT,
                                                      const float* __restrict__ bias,
                                                      float* __restrict__ out,
                                                      float* __restrict__ stats) {
    __shared__ float sb[8];
    int b = blockIdx.y, tx = threadIdx.x;
    int cg = tx & 15, pp = tx >> 4;
    int p = blockIdx.x * 16 + pp;
    int xx = p & 63, yy = p >> 6;
    int c0 = cg * 8;
    float acc[8], ctr[8];
#pragma unroll
    for (int j = 0; j < 8; ++j) acc[j] = bias[c0 + j];
#pragma unroll
    for (int dy = -1; dy <= 1; ++dy) {
        int y2 = yy + dy;
        if (y2 < 0 || y2 >= 64) continue;
#pragma unroll
        for (int dx = -1; dx <= 1; ++dx) {
            int x2 = xx + dx;
            if (x2 < 0 || x2 >= 64) continue;
            const float* ip = &in[((size_t)b * NPIX + y2 * 64 + x2) * 128 + c0];
            float4 v0 = *(const float4*)ip;
            float4 v1 = *(const float4*)(ip + 4);
            const float* wr = wT + ((dy + 1) * 3 + dx + 1) * 128 + c0;
            acc[0] += v0.x * wr[0]; acc[1] += v0.y * wr[1];
            acc[2] += v0.z * wr[2]; acc[3] += v0.w * wr[3];
            acc[4] += v1.x * wr[4]; acc[5] += v1.y * wr[5];
            acc[6] += v1.z * wr[6]; acc[7] += v1.w * wr[7];
            if (dy == 0 && dx == 0) {
                ctr[0] = v0.x; ctr[1] = v0.y; ctr[2] = v0.z; ctr[3] = v0.w;
                ctr[4] = v1.x; ctr[5] = v1.y; ctr[6] = v1.z; ctr[7] = v1.w;
            }
        }
    }
    float s = 0.f, s2 = 0.f;
    float r[8];
#pragma unroll
    for (int j = 0; j < 8; ++j) {
        r[j] = ctr[j] + acc[j];
        s += r[j]; s2 += r[j] * r[j];
    }
    float* op = &out[((size_t)b * NPIX + p) * 128 + c0];
    *(float4*)op = make_float4(r[0], r[1], r[2], r[3]);
    *(float4*)(op + 4) = make_float4(r[4], r[5], r[6], r[7]);
#pragma unroll
    for (int off = 32; off > 0; off >>= 1) {
        s += __shfl_down(s, off, 64);
        s2 += __shfl_down(s2, off, 64);
    }
    int wv = tx >> 6;
    if ((tx & 63) == 0) { sb[wv] = s; sb[4 + wv] = s2; }
    __syncthreads();
    if (tx == 0) {
        int slot = (b * 8 + (blockIdx.x & 7)) * 16;
        atomicAdd(&stats[slot], sb[0] + sb[1] + sb[2] + sb[3]);
        atomicAdd(&stats[slot + 1], sb[4] + sb[5] + sb[6] + sb[7]);
    }
}

// ---------------- NHWC bf16 dwconv3 + bias + relu -> bf16 ----------------
__global__ __launch_bounds__(256) void dwc_bf16_kernel(const unsigned short* __restrict__ in,
                                                       const float* __restrict__ wT,
                                                       const float* __restrict__ bias,
                                                       unsigned short* __restrict__ out) {
    int b = blockIdx.y, tx = threadIdx.x;
    int cg = tx & 15, pp = tx >> 4;
    int p = blockIdx.x * 16 + pp;
    int xx = p & 63, yy = p >> 6;
    int c0 = cg * 8;
    float acc[8];
#pragma unroll
    for (int j = 0; j < 8; ++j) acc[j] = bias[c0 + j];
#pragma unroll
    for (int dy = -1; dy <= 1; ++dy) {
        int y2 = yy + dy;
        if (y2 < 0 || y2 >= 64) continue;
#pragma unroll
        for (int dx = -1; dx <= 1; ++dx) {
            int x2 = xx + dx;
            if (x2 < 0 || x2 >= 64) continue;
            unsigned short v[8];
            *(uint4*)v = *(const uint4*)&in[((size_t)b * NPIX + y2 * 64 + x2) * 128 + c0];
            const float* wr = wT + ((dy + 1) * 3 + dx + 1) * 128 + c0;
#pragma unroll
            for (int j = 0; j < 8; ++j) acc[j] += b2f(v[j]) * wr[j];
        }
    }
    unsigned short o[8];
#pragma unroll
    for (int j = 0; j < 8; ++j) o[j] = f2b(fmaxf(acc[j], 0.f));
    *(uint4*)&out[((size_t)b * NPIX + p) * 128 + c0] = *(uint4*)o;
}

// ---------------- conv1x1 via bf16 MFMA, 128out x 64px tile (y-parallel form) ----------------
__global__ __launch_bounds__(256) void conv_mfma_kernel(const unsigned short* __restrict__ in_t,
                                                        const float* __restrict__ in_f32,
                                                        const float* __restrict__ gst,
                                                        const float* __restrict__ gg,
                                                        const float* __restrict__ gbta,
                                                        const unsigned short* __restrict__ w,
                                                        const float* __restrict__ bias,
                                                        const float* __restrict__ res,
                                                        float* __restrict__ out,
                                                        unsigned short* __restrict__ out_t,
                                                        unsigned short* __restrict__ out_t2,
                                                        int Cin, int Cout, int relu, int nchw) {
    __shared__ __align__(16) unsigned short A_s[128][136];
    __shared__ __align__(16) unsigned short B_s[64][136];
    int b = blockIdx.z, p0 = blockIdx.x * 64, o0 = blockIdx.y * 128;
    int tx = threadIdx.x;
    int wave = tx >> 6, lane = tx & 63;
    int wm = wave & 1, wn = wave >> 1;
    int quad = lane >> 4, l16 = lane & 15;

    float mu = 0.f, rr = 1.f;
    if (in_f32) {
        float su = 0.f, sq = 0.f;
#pragma unroll
        for (int sl = 0; sl < 8; ++sl) {
            su += gst[(b * 8 + sl) * 16];
            sq += gst[(b * 8 + sl) * 16 + 1];
        }
        const float n = 1.f / (float)(CDIM * NPIX);
        mu = su * n;
        float var = sq * n - mu * mu;
        rr = rsqrtf(var + EPSN);
    }

    f32x4 acc[4][2];
#pragma unroll
    for (int mt = 0; mt < 4; ++mt) {
#pragma unroll
        for (int r = 0; r < 4; ++r) {
            float bv = bias[o0 + wm * 64 + mt * 16 + quad * 4 + r];
#pragma unroll
            for (int nt = 0; nt < 2; ++nt) acc[mt][nt][r] = bv;
        }
    }

    for (int k0 = 0; k0 < Cin; k0 += 128) {
#pragma unroll
        for (int j = 0; j < 8; ++j) {
            int idx = tx + 256 * j;
            int row = idx >> 4, c16 = idx & 15;
            *(uint4*)&A_s[row][c16 * 8] =
                *(const uint4*)&w[(size_t)(o0 + row) * Cin + k0 + c16 * 8];
        }
        if (in_f32) {
#pragma unroll
            for (int j = 0; j < 4; ++j) {
                int idx = tx + 256 * j;
                int row = idx >> 4, c16 = idx & 15;
                int ch = c16 * 8;  // Cin==128
                const float* ip = &in_f32[((size_t)b * NPIX + p0 + row) * 128 + ch];
                float4 v0 = *(const float4*)ip;
                float4 v1 = *(const float4*)(ip + 4);
                unsigned short o[8];
                o[0] = f2b((v0.x - mu) * rr * gg[ch + 0] + gbta[ch + 0]);
                o[1] = f2b((v0.y - mu) * rr * gg[ch + 1] + gbta[ch + 1]);
                o[2] = f2b((v0.z - mu) * rr * gg[ch + 2] + gbta[ch + 2]);
                o[3] = f2b((v0.w - mu) * rr * gg[ch + 3] + gbta[ch + 3]);
                o[4] = f2b((v1.x - mu) * rr * gg[ch + 4] + gbta[ch + 4]);
                o[5] = f2b((v1.y - mu) * rr * gg[ch + 5] + gbta[ch + 5]);
                o[6] = f2b((v1.z - mu) * rr * gg[ch + 6] + gbta[ch + 6]);
                o[7] = f2b((v1.w - mu) * rr * gg[ch + 7] + gbta[ch + 7]);
                *(uint4*)&B_s[row][c16 * 8] = *(uint4*)o;
            }
        } else {
#pragma unroll
            for (int j = 0; j < 4; ++j) {
                int idx = tx + 256 * j;
                int row = idx >> 4, c16 = idx & 15;
                *(uint4*)&B_s[row][c16 * 8] =
                    *(const uint4*)&in_t[((size_t)b * NPIX + p0 + row) * Cin + k0 + c16 * 8];
            }
        }
        __syncthreads();
#pragma unroll
        for (int ks = 0; ks < 128; ks += 32) {
            short8 af[4], bf[2];
#pragma unroll
            for (int mt = 0; mt < 4; ++mt)
                af[mt] = *(const short8*)&A_s[wm * 64 + mt * 16 + l16][ks + quad * 8];
#pragma unroll
            for (int nt = 0; nt < 2; ++nt)
                bf[nt] = *(const short8*)&B_s[wn * 32 + nt * 16 + l16][ks + quad * 8];
#pragma unroll
            for (int mt = 0; mt < 4; ++mt)
#pragma unroll
                for (int nt = 0; nt < 2; ++nt)
                    acc[mt][nt] = __builtin_amdgcn_mfma_f32_16x16x32_bf16(
                        af[mt], bf[nt], acc[mt][nt], 0, 0, 0);
        }
        __syncthreads();
    }

    int dorelu = (relu == 1) || (relu == 2 && blockIdx.y == 0);
    if (out_t) {
#pragma unroll
        for (int mt = 0; mt < 4; ++mt) {
#pragma unroll
            for (int nt = 0; nt < 2; ++nt) {
                int p = p0 + wn * 32 + nt * 16 + l16;
                int ob = o0 + wm * 64 + mt * 16 + quad * 4;
                unsigned short* dbuf = out_t;
                int oc = ob;
                if (out_t2 && o0 >= 128) { dbuf = out_t2; oc = ob - 128; }
                ushort4 u;
                float v0 = acc[mt][nt][0], v1 = acc[mt][nt][1];
                float v2 = acc[mt][nt][2], v3 = acc[mt][nt][3];
                if (dorelu) { v0 = fmaxf(v0, 0.f); v1 = fmaxf(v1, 0.f);
                              v2 = fmaxf(v2, 0.f); v3 = fmaxf(v3, 0.f); }
                u.x = f2b(v0); u.y = f2b(v1); u.z = f2b(v2); u.w = f2b(v3);
                *(ushort4*)&dbuf[((size_t)b * NPIX + p) * Cout + oc] = u;
            }
        }
    } else if (!nchw) {
#pragma unroll
        for (int mt = 0; mt < 4; ++mt) {
#pragma unroll
            for (int nt = 0; nt < 2; ++nt) {
                int p = p0 + wn * 32 + nt * 16 + l16;
                int ob = o0 + wm * 64 + mt * 16 + quad * 4;
                size_t ix = ((size_t)b * NPIX + p) * Cout + ob;
                float4 v = make_float4(acc[mt][nt][0], acc[mt][nt][1],
                                       acc[mt][nt][2], acc[mt][nt][3]);
                if (dorelu) { v.x = fmaxf(v.x, 0.f); v.y = fmaxf(v.y, 0.f);
                              v.z = fmaxf(v.z, 0.f); v.w = fmaxf(v.w, 0.f); }
                if (res) {
                    float4 rv = *(const float4*)&res[ix];
                    v.x += rv.x; v.y += rv.y; v.z += rv.z; v.w += rv.w;
                }
                *(float4*)&out[ix] = v;
            }
        }
    } else {
        float* outb = out + (size_t)b * Cout * NPIX;
#pragma unroll
        for (int mt = 0; mt < 4; ++mt) {
#pragma unroll
            for (int nt = 0; nt < 2; ++nt) {
                int p = p0 + wn * 32 + nt * 16 + l16;
                int ob = o0 + wm * 64 + mt * 16 + quad * 4;
                float4 rv = make_float4(0.f, 0.f, 0.f, 0.f);
                if (res) rv = *(const float4*)&res[((size_t)b * NPIX + p) * 128 + ob];
#pragma unroll
                for (int r = 0; r < 4; ++r) {
                    float v = acc[mt][nt][r];
                    if (dorelu) v = fmaxf(v, 0.f);
                    v += (r == 0 ? rv.x : r == 1 ? rv.y : r == 2 ? rv.z : rv.w);
                    outb[(size_t)(ob + r) * NPIX + p] = v;
                }
            }
        }
    }
}

// ---------------- MFMA window attention, both orientations in one launch ----------------
// q pre-scaled by log2(e) -> native exp2; row-sum via ones-row at PV A row 16 (o_acc[8]).
// K STAGED IN LDS: kf gathers depended only on (l32,half,nt) — all 4 waves issued
// byte-identical scattered 16B loads (4x redundant). K slice (256 tok x 16ch = 8KB) is now
// staged once in the prologue alongside V; kf becomes ds_read_b128 from Kt[256][24]
// (rows padded 32B->48B: bank start (12*l)%32 covers all 32 banks every 8 lanes ->
// conflict-free at the b128 minimum). nt outer / both q-slices inner (round 3).
// P redistribution via v_permlane32_swap_b32; V padded to 32 rows (row16=ones, 17-31=0).
__global__ __launch_bounds__(256) void attn_dual_kernel(const unsigned short* __restrict__ t_t,
                                                        float* __restrict__ a0,
                                                        float* __restrict__ a1) {
    __shared__ __align__(16) unsigned short Vt[32][264];
    __shared__ __align__(16) unsigned short Kt[256][24];
    int wi = blockIdx.x, head = blockIdx.y;
    int z = blockIdx.z;
    int b = z >> 1, which = z & 1;
    int qoff = which ? 384 : 0;
    int koff = which ? 512 : 128;
    int mode = which;
    float* a_out = which ? a1 : a0;
    int tx = threadIdx.x;
    int wave = tx >> 6, l = tx & 63;
    int l32 = l & 31, half = l >> 5;
    const size_t base = (size_t)b * NPIX;
    const int hc = head * 16;

    {
        int p = tok2pix(mode, wi, tx);
        const unsigned short* vp = &t_t[(base + p) * 640 + 256 + hc];
        const unsigned short* kp = &t_t[(base + p) * 640 + koff + hc];
        unsigned short tmp[16];
        *(uint4*)&tmp[0] = *(const uint4*)vp;
        *(uint4*)&tmp[8] = *(const uint4*)(vp + 8);
        uint4 k0 = *(const uint4*)kp;
        uint4 k1 = *(const uint4*)(kp + 8);
        *(uint4*)&Kt[tx][0] = k0;
        *(uint4*)&Kt[tx][8] = k1;
#pragma unroll
        for (int d = 0; d < 16; ++d) Vt[d][tx] = tmp[d];
        Vt[16][tx] = (unsigned short)0x3F80;  // bf16 1.0 — row-sum row
#pragma unroll
        for (int d = 17; d < 32; ++d) Vt[d][tx] = 0;
    }
    __syncthreads();

    f32x16 zzero;
#pragma unroll
    for (int r = 0; r < 16; ++r) zzero[r] = 0.f;

    const unsigned short* qb = t_t + base * 640 + hc + half * 8 + qoff;

    int qp0 = tok2pix(mode, wi, (0 * 4 + wave) * 32 + l32);
    int qp1 = tok2pix(mode, wi, (1 * 4 + wave) * 32 + l32);
    short8 qf0 = *(const short8*)&qb[(size_t)qp0 * 640];
    short8 qf1 = *(const short8*)&qb[(size_t)qp1 * 640];
    f32x16 oa0 = zzero, oa1 = zzero;

#pragma unroll
    for (int nt = 0; nt < 8; ++nt) {
        short8 kf = *(const short8*)&Kt[nt * 32 + l32][half * 8];
        short8 vf0 = *(const short8*)&Vt[l32][nt * 32 + half * 8];
        short8 vf1 = *(const short8*)&Vt[l32][nt * 32 + 16 + half * 8];
#pragma unroll
        for (int qi = 0; qi < 2; ++qi) {
            short8 qf = (qi == 0) ? qf0 : qf1;
            f32x16 s = __builtin_amdgcn_mfma_f32_32x32x16_bf16(kf, qf, zzero, 0, 0, 0);
            unsigned int pk[8];
#pragma unroll
            for (int i = 0; i < 8; ++i) {
                float e0 = __builtin_amdgcn_exp2f(s[2 * i]);
                float e1 = __builtin_amdgcn_exp2f(s[2 * i + 1]);
                pk[i] = __builtin_amdgcn_perm(__float_as_uint(e1), __float_as_uint(e0),
                                              0x07060302u);
            }
            // redistribute halves: (u0[0],u0[2]) = swap(pk0,pk2), etc.
            pl32swap(pk[0], pk[2]);
            pl32swap(pk[1], pk[3]);
            pl32swap(pk[4], pk[6]);
            pl32swap(pk[5], pk[7]);
            unsigned int u0[4] = {pk[0], pk[1], pk[2], pk[3]};
            unsigned int u1[4] = {pk[4], pk[5], pk[6], pk[7]};
            if (qi == 0) {
                oa0 = __builtin_amdgcn_mfma_f32_32x32x16_bf16(vf0, *(short8*)u0, oa0, 0, 0, 0);
                oa0 = __builtin_amdgcn_mfma_f32_32x32x16_bf16(vf1, *(short8*)u1, oa0, 0, 0, 0);
            } else {
                oa1 = __builtin_amdgcn_mfma_f32_32x32x16_bf16(vf0, *(short8*)u0, oa1, 0, 0, 0);
                oa1 = __builtin_amdgcn_mfma_f32_32x32x16_bf16(vf1, *(short8*)u1, oa1, 0, 0, 0);
            }
        }
    }

    // epilogue for both q-slices: row 16 of PV output = sum_t P[t][col] (r=8)
#pragma unroll
    for (int qi = 0; qi < 2; ++qi) {
        f32x16 oc = (qi == 0) ? oa0 : oa1;
        int qp = (qi == 0) ? qp0 : qp1;
        float rs = oc[8];
        rs += __shfl_xor(rs, 32, 64);
        float rinv = 1.f / rs;
        // d = (r&3) + 8*(r>>2) + 4*half  ->  two contiguous float4 runs
        float* dst = a_out + (base + qp) * 128 + hc + 4 * half;
        float4 s0 = make_float4(oc[0] * rinv, oc[1] * rinv,
                                oc[2] * rinv, oc[3] * rinv);
        float4 s1 = make_float4(oc[4] * rinv, oc[5] * rinv,
                                oc[6] * rinv, oc[7] * rinv);
        *(float4*)dst = s0;
        *(float4*)(dst + 8) = s1;
    }
}

// ---------------- m_t = bf16((a0 + a1 + cpe(v0)) * act_res)  (all NHWC) ----------------
__global__ __launch_bounds__(256) void mul3_cpe_kernel(const float* __restrict__ a0,
                                                       const float* __restrict__ a1,
                                                       const unsigned short* __restrict__ act,
                                                       const unsigned short* __restrict__ t_t,
                                                       const float* __restrict__ wT,
                                                       const float* __restrict__ bsum,
                                                       unsigned short* __restrict__ dst) {
    int b = blockIdx.y;
    int tx = threadIdx.x;
    int cg = tx & 15, pp = tx >> 4;
    int p = blockIdx.x * 16 + pp;
    int xx = p & 63, yy = p >> 6;
    int c0 = cg * 8;
    float acc[8];
#pragma unroll
    for (int j = 0; j < 8; ++j) acc[j] = bsum[c0 + j];
#pragma unroll
    for (int dy = -1; dy <= 1; ++dy) {
        int y2 = yy + dy;
        if (y2 < 0 || y2 >= 64) continue;
#pragma unroll
        for (int dx = -1; dx <= 1; ++dx) {
            int x2 = xx + dx;
            if (x2 < 0 || x2 >= 64) continue;
            int pn = y2 * 64 + x2;
            unsigned short v[8];
            *(uint4*)v = *(const uint4*)&t_t[((size_t)b * NPIX + pn) * 640 + 256 + c0];
            const float* wr = wT + ((dy + 1) * 3 + dx + 1) * 128 + c0;
#pragma unroll
            for (int j = 0; j < 8; ++j) acc[j] += b2f(v[j]) * wr[j];
        }
    }
    size_t base = ((size_t)b * NPIX + p) * 128 + c0;
    float4 x0 = *(const float4*)&a0[base];
    float4 x1 = *(const float4*)&a0[base + 4];
    float4 y0 = *(const float4*)&a1[base];
    float4 y1 = *(const float4*)&a1[base + 4];
    unsigned short t[8];
    *(uint4*)t = *(const uint4*)&act[base];
    unsigned short r[8];
    r[0] = f2b((x0.x + y0.x + acc[0]) * b2f(t[0]));
    r[1] = f2b((x0.y + y0.y + acc[1]) * b2f(t[1]));
    r[2] = f2b((x0.z + y0.z + acc[2]) * b2f(t[2]));
    r[3] = f2b((x0.w + y0.w + acc[3]) * b2f(t[3]));
    r[4] = f2b((x1.x + y1.x + acc[4]) * b2f(t[4]));
    r[5] = f2b((x1.y + y1.y + acc[5]) * b2f(t[5]));
    r[6] = f2b((x1.z + y1.z + acc[6]) * b2f(t[6]));
    r[7] = f2b((x1.w + y1.w + acc[7]) * b2f(t[7]));
    *(uint4*)&dst[base] = *(uint4*)r;
}

extern "C" void kernel_launch(void* const* d_in, const int* in_sizes, int n_in,
                              void* d_out, int out_size, void* d_ws, size_t ws_size,
                              hipStream_t stream) {
    const float* x       = (const float*)d_in[0];
    const float* eca_w   = (const float*)d_in[1];
    const float* esa_al  = (const float*)d_in[2];
    const float* cpe1_w  = (const float*)d_in[3];  const float* cpe1_b = (const float*)d_in[4];
    const float* g1      = (const float*)d_in[5];  const float* b1     = (const float*)d_in[6];
    const float* actp_w  = (const float*)d_in[7];  const float* actp_b = (const float*)d_in[8];
    const float* inp_w   = (const float*)d_in[9];  const float* inp_b  = (const float*)d_in[10];
    const float* dwc_w   = (const float*)d_in[11]; const float* dwc_b  = (const float*)d_in[12];
    const float* qkv_w   = (const float*)d_in[13]; const float* qkv_b  = (const float*)d_in[14];
    const float* eaax_w  = (const float*)d_in[15]; const float* eaax_b = (const float*)d_in[16];
    const float* eaay_w  = (const float*)d_in[17]; const float* eaay_b = (const float*)d_in[18];
    const float* outp_w  = (const float*)d_in[19]; const float* outp_b = (const float*)d_in[20];
    const float* cpe2_w  = (const float*)d_in[21]; const float* cpe2_b = (const float*)d_in[22];
    const float* g2      = (const float*)d_in[23]; const float* b2     = (const float*)d_in[24];
    const float* mlp1_w  = (const float*)d_in[25]; const float* mlp1_b = (const float*)d_in[26];
    const float* mlp2_w  = (const float*)d_in[27]; const float* mlp2_b = (const float*)d_in[28];

    float* ws = (float*)d_ws;
    unsigned short* U = (unsigned short*)d_ws;
    const size_t E = (size_t)BATCH * CDIM * NPIX;  // 4,194,304

    float* y_nhwc  = ws;                // [0,E)  esa out; later a0
    float* a0      = ws;
    float* sc_nhwc = ws + E;            // [E,2E) shortcut (live to outp)
    unsigned short* act_t = U + 5 * E;  // [2.5E,3E)
    unsigned short* it_t  = U + 6 * E;  // [3E,3.5E)
    unsigned short* tin_t = U + 7 * E;  // [3.5E,4E)
    float* a1      = ws + 4 * E;        // [4E,5E)
    unsigned short* t_t   = U + 10 * E; // [5E,7.5E)
    unsigned short* m_t   = U + 15 * E; // [7.5E,8E)
    float* out_nhwc = ws + 8 * E;       // [8E,9E)
    float* out2    = ws + 2 * E;        // [2E,3E)  (act_t dead by then)
    unsigned short* hid_t = U + 10 * E; // [5E,7E)  (t_t dead after mul3_cpe)
    unsigned short* wpool = U + 20 * E; // 262144 bf16
    unsigned short* wq  = wpool;
    unsigned short* wm1 = wpool + 81920;
    unsigned short* wm2 = wpool + 147456;
    unsigned short* wai = wpool + 212992;   // actp rows 0-127, inp rows 128-255 (contiguous)
    unsigned short* wo  = wpool + 245760;
    float* fb     = ws + 10 * E + 131072;
    float* meanb  = fb;            // 1024
    float* gstats = fb + 2048;     // 2048: gn1 [0,1024), gn2 [1024,2048)
    float* qb_r   = fb + 4096;     // 640
    float* wsT    = fb + 4736;     // 1152
    float* bsum   = fb + 5888;     // 128
    float* cpe1T  = fb + 6016;     // 1152
    float* dwcT   = fb + 7168;     // 1152
    float* cpe2T  = fb + 8320;     // 1152
    float* abi    = fb + 9472;     // 256

    convert_w_kernel<<<1054, 256, 0, stream>>>(qkv_w, mlp1_w, mlp2_w, actp_w, inp_w, outp_w,
                                               qkv_b, eaax_w, eaax_b, eaay_w, eaay_b,
                                               cpe1_w, dwc_w, cpe2_w, actp_b, inp_b,
                                               wpool, qb_r, wsT, bsum, cpe1T, dwcT, cpe2T, abi,
                                               gstats);

    // 1) ECA + ESA (gate inline) with transpose -> y (f32 NHWC)
    mean_bc_kernel<<<BATCH * CDIM, 256, 0, stream>>>(x, meanb);
    esa_tr_kernel<<<dim3(64, BATCH), 256, 0, stream>>>(x, meanb, eca_w, esa_al, y_nhwc);
    // 2) shortcut = y + cpe1(y), fused GN1 stats
    cpe_f32_kernel<<<dim3(256, BATCH), 256, 0, stream>>>(y_nhwc, cpe1T, cpe1_b, sc_nhwc, gstats);
    // 3+4+5a) merged actp+inp conv with fused GN1 apply: sc_nhwc -> act_t (relu), it_t
    conv_mfma_kernel<<<dim3(64, 2, BATCH), 256, 0, stream>>>(nullptr, sc_nhwc, gstats, g1, b1,
                                                             wai, abi, nullptr, nullptr,
                                                             act_t, it_t, 128, 128, 2, 0);
    // 5b) tin = relu(dwc(it))
    dwc_bf16_kernel<<<dim3(256, BATCH), 256, 0, stream>>>(it_t, dwcT, dwc_b, tin_t);
    // 6) qkv -> t_t (bf16 NHWC, 640 grouped; q groups pre-scaled by log2e)
    conv_mfma_kernel<<<dim3(64, 5, BATCH), 256, 0, stream>>>(tin_t, nullptr, nullptr, nullptr,
                                                             nullptr, wq, qb_r, nullptr, nullptr,
                                                             t_t, nullptr, 128, 640, 0, 0);
    // 7) both attentions -> a0, a1
    attn_dual_kernel<<<dim3(16, 8, 2 * BATCH), 256, 0, stream>>>(t_t, a0, a1);
    // 8) m_t = bf16((a0+a1+cpe(v0))*act) ; out = outp(m) + shortcut -> out_nhwc
    mul3_cpe_kernel<<<dim3(256, BATCH), 256, 0, stream>>>(a0, a1, act_t, t_t, wsT, bsum, m_t);
    conv_mfma_kernel<<<dim3(64, 1, BATCH), 256, 0, stream>>>(m_t, nullptr, nullptr, nullptr,
                                                             nullptr, wo, outp_b, sc_nhwc,
                                                             out_nhwc, nullptr, nullptr,
                                                             128, 128, 0, 0);
    // 9) out2 = out + cpe2(out), fused GN2 stats
    cpe_f32_kernel<<<dim3(256, BATCH), 256, 0, stream>>>(out_nhwc, cpe2T, cpe2_b, out2,
                                                         gstats + 1024);
    // 10+11) mlp1 with fused GN2 apply -> hid_t ; mlp2 + out2 residual -> d_out (NCHW)
    conv_mfma_kernel<<<dim3(64, 4, BATCH), 256, 0, stream>>>(nullptr, out2, gstats + 1024, g2, b2,
                                                             wm1, mlp1_b, nullptr, nullptr,
                                                             hid_t, nullptr, 128, 512, 1, 0);
    conv_mfma_kernel<<<dim3(64, 1, BATCH), 256, 0, stream>>>(hid_t, nullptr, nullptr, nullptr,
                                                             nullptr, wm2, mlp2_b, out2,
                                                             (float*)d_out, nullptr, nullptr,
                                                             512, 128, 0, 1);
}

// Round 5
// 290.601 us; speedup vs baseline: 1.1105x; 1.0058x over previous
//
#include <hip/hip_runtime.h>

#define NPIX 4096
#define CDIM 128
#define BATCH 8
#define EPSN 1e-5f
#define LOG2E 1.44269504088896340736f

typedef __attribute__((ext_vector_type(8))) short short8;
typedef __attribute__((ext_vector_type(4))) float f32x4;
typedef __attribute__((ext_vector_type(16))) float f32x16;

__device__ __forceinline__ float sigmoidf_(float x) { return 1.f / (1.f + __expf(-x)); }

__device__ __forceinline__ unsigned short f2b(float f) {
    unsigned int u = __float_as_uint(f);
    unsigned int r = (u + 0x7FFF + ((u >> 16) & 1)) >> 16;  // RNE
    return (unsigned short)r;
}
__device__ __forceinline__ float b2f(unsigned short u) {
    return __uint_as_float((unsigned int)u << 16);
}

// exchange: after call, a = {a.lo, b.lo->hi}, b = {a.hi->lo, b.hi}
// (v_permlane32_swap_b32 swaps upper 32 lanes of a with lower 32 lanes of b)
__device__ __forceinline__ void pl32swap(unsigned int& a, unsigned int& b) {
    asm("v_permlane32_swap_b32 %0, %1" : "+v"(a), "+v"(b));
}

// window token -> pixel index
__device__ __forceinline__ int tok2pix(int mode, int wi, int l) {
    return (mode == 0) ? ((l >> 2) * 64 + wi * 4 + (l & 3))
                       : ((wi * 4 + (l >> 6)) * 64 + (l & 63));
}

// ---------------- weight conversion / reorder / transposes / gstats zeroing ----------------
// q0/q1 weight+bias groups pre-scaled by log2(e) so attention can use native exp2.
__global__ __launch_bounds__(256) void convert_w_kernel(const float* __restrict__ qkv_w,
                                                        const float* __restrict__ mlp1_w,
                                                        const float* __restrict__ mlp2_w,
                                                        const float* __restrict__ actp_w,
                                                        const float* __restrict__ inp_w,
                                                        const float* __restrict__ outp_w,
                                                        const float* __restrict__ qkv_b,
                                                        const float* __restrict__ eaax_w,
                                                        const float* __restrict__ eaax_b,
                                                        const float* __restrict__ eaay_w,
                                                        const float* __restrict__ eaay_b,
                                                        const float* __restrict__ cpe1_w,
                                                        const float* __restrict__ dwc_w,
                                                        const float* __restrict__ cpe2_w,
                                                        const float* __restrict__ actp_b,
                                                        const float* __restrict__ inp_b,
                                                        unsigned short* __restrict__ dst,
                                                        float* __restrict__ qb_r,
                                                        float* __restrict__ wsT,
                                                        float* __restrict__ bsum,
                                                        float* __restrict__ cpe1T,
                                                        float* __restrict__ dwcT,
                                                        float* __restrict__ cpe2T,
                                                        float* __restrict__ abi,
                                                        float* __restrict__ gstats) {
    int i = blockIdx.x * 256 + threadIdx.x;
    if (i >= 267776) {
        if (i < 269824) gstats[i - 267776] = 0.f;
        return;
    }
    if (i < 262144) {
        float v;
        if (i < 81920) {
            int o = i >> 7, c = i & 127;              // reordered: o_new = g*128+cc
            int g = o >> 7;
            v = qkv_w[(size_t)(5 * (o & 127) + g) * 128 + c];
            if (g == 0 || g == 3) v *= LOG2E;         // q0/q1 pre-scale for exp2
        } else if (i < 147456) v = mlp1_w[i - 81920];
        else if (i < 212992)   v = mlp2_w[i - 147456];
        else if (i < 229376)   v = actp_w[i - 212992];
        else if (i < 245760)   v = inp_w[i - 229376];
        else                   v = outp_w[i - 245760];
        dst[i] = f2b(v);
    } else {
        int j = i - 262144;
        if (j < 640) {
            int g = j >> 7;
            float v = qkv_b[5 * (j & 127) + g];
            if (g == 0 || g == 3) v *= LOG2E;
            qb_r[j] = v;
        }
        else if (j < 1792) {
            int idx = j - 640; int k = idx >> 7, c = idx & 127;
            wsT[idx] = eaax_w[c * 9 + k] + eaay_w[c * 9 + k];
        } else if (j < 1920) bsum[j - 1792] = eaax_b[j - 1792] + eaay_b[j - 1792];
        else if (j < 3072) {
            int idx = j - 1920; int k = idx >> 7, c = idx & 127;
            cpe1T[idx] = cpe1_w[c * 9 + k];
        } else if (j < 4224) {
            int idx = j - 3072; int k = idx >> 7, c = idx & 127;
            dwcT[idx] = dwc_w[c * 9 + k];
        } else if (j < 5376) {
            int idx = j - 4224; int k = idx >> 7, c = idx & 127;
            cpe2T[idx] = cpe2_w[c * 9 + k];
        } else {
            int idx = j - 5376;
            abi[idx] = (idx < 128) ? actp_b[idx] : inp_b[idx - 128];
        }
    }
}

// ---------------- per-(b,c) mean over HW (x is NCHW input) ----------------
__global__ __launch_bounds__(256) void mean_bc_kernel(const float* __restrict__ x,
                                                      float* __restrict__ mean) {
    __shared__ float sb[4];
    int bc = blockIdx.x;
    const float* p = x + (size_t)bc * NPIX;
    float s = 0.f;
    for (int i = threadIdx.x; i < NPIX; i += 256) s += p[i];
#pragma unroll
    for (int off = 32; off > 0; off >>= 1) s += __shfl_down(s, off, 64);
    if ((threadIdx.x & 63) == 0) sb[threadIdx.x >> 6] = s;
    __syncthreads();
    if (threadIdx.x == 0) mean[bc] = (sb[0] + sb[1] + sb[2] + sb[3]) * (1.f / (float)NPIX);
}

// ---------------- ESA+ECA fused (gate computed inline) with NCHW->NHWC transpose ----------------
__global__ __launch_bounds__(256) void esa_tr_kernel(const float* __restrict__ x,
                                                     const float* __restrict__ mean,
                                                     const float* __restrict__ w5,
                                                     const float* __restrict__ alpha_p,
                                                     float* __restrict__ y) {
    __shared__ float tile[128][65];
    __shared__ float smx[4][64], smn[4][64], ssc[64], gat[128];
    int b = blockIdx.y, p0 = blockIdx.x * 64;
    int tx = threadIdx.x, pl = tx & 63, part = tx >> 6;
    const float* xb = x + (size_t)b * CDIM * NPIX;
    const float* mb = mean + b * CDIM;
    for (int c = part; c < CDIM; c += 4)
        tile[c][pl] = xb[(size_t)c * NPIX + p0 + pl];
    __syncthreads();
    float mx = -1e30f, mn = 1e30f;
#pragma unroll
    for (int cc = 0; cc < 32; ++cc) {
        int c = part * 32 + cc;
        float v = tile[c][pl] - mb[c];
        mx = fmaxf(mx, v); mn = fminf(mn, v);
    }
    smx[part][pl] = mx; smn[part][pl] = mn;
    __syncthreads();
    if (tx < 128) {
        float s = 0.f;
#pragma unroll
        for (int k = 0; k < 5; ++k) {
            int cc = tx + k - 2;
            if (cc >= 0 && cc < CDIM) s += w5[k] * mb[cc];
        }
        gat[tx] = sigmoidf_(s);
    }
    if (part == 0) {
        float m1 = fmaxf(fmaxf(smx[0][pl], smx[1][pl]), fmaxf(smx[2][pl], smx[3][pl]));
        float m2 = fminf(fminf(smn[0][pl], smn[1][pl]), fminf(smn[2][pl], smn[3][pl]));
        float a = alpha_p[0];
        ssc[pl] = sigmoidf_(m1) * a + sigmoidf_(m2) * (1.f - a);
    }
    __syncthreads();
    int c2 = tx & 127, pr = tx >> 7;
    float* yb = y + ((size_t)b * NPIX + p0) * CDIM;
    float gv = gat[c2];
    for (int p = pr; p < 64; p += 2)
        yb[(size_t)p * CDIM + c2] = tile[c2][p] * (gv + ssc[p]);
}

// ---------------- NHWC f32 dwconv3 + residual + fused PER-BATCH GN stats (8 spread slots) ----------------
__global__ __launch_bounds__(256) void cpe_f32_kernel(const float* __restrict__ in,
                                                      const float* __restrict__ wT,
                                                      const float* __restrict__ bias,
                                                      float* __restrict__ out,
                                                      float* __restrict__ stats) {
    __shared__ float sb[8];
    int b = blockIdx.y, tx = threadIdx.x;
    int cg = tx & 15, pp = tx >> 4;
    int p = blockIdx.x * 16 + pp;
    int xx = p & 63, yy = p >> 6;
    int c0 = cg * 8;
    float acc[8], ctr[8];
#pragma unroll
    for (int j = 0; j < 8; ++j) acc[j] = bias[c0 + j];
#pragma unroll
    for (int dy = -1; dy <= 1; ++dy) {
        int y2 = yy + dy;
        if (y2 < 0 || y2 >= 64) continue;
#pragma unroll
        for (int dx = -1; dx <= 1; ++dx) {
            int x2 = xx + dx;
            if (x2 < 0 || x2 >= 64) continue;
            const float* ip = &in[((size_t)b * NPIX + y2 * 64 + x2) * 128 + c0];
            float4 v0 = *(const float4*)ip;
            float4 v1 = *(const float4*)(ip + 4);
            const float* wr = wT + ((dy + 1) * 3 + dx + 1) * 128 + c0;
            acc[0] += v0.x * wr[0]; acc[1] += v0.y * wr[1];
            acc[2] += v0.z * wr[2]; acc[3] += v0.w * wr[3];
            acc[4] += v1.x * wr[4]; acc[5] += v1.y * wr[5];
            acc[6] += v1.z * wr[6]; acc[7] += v1.w * wr[7];
            if (dy == 0 && dx == 0) {
                ctr[0] = v0.x; ctr[1] = v0.y; ctr[2] = v0.z; ctr[3] = v0.w;
                ctr[4] = v1.x; ctr[5] = v1.y; ctr[6] = v1.z; ctr[7] = v1.w;
            }
        }
    }
    float s = 0.f, s2 = 0.f;
    float r[8];
#pragma unroll
    for (int j = 0; j < 8; ++j) {
        r[j] = ctr[j] + acc[j];
        s += r[j]; s2 += r[j] * r[j];
    }
    float* op = &out[((size_t)b * NPIX + p) * 128 + c0];
    *(float4*)op = make_float4(r[0], r[1], r[2], r[3]);
    *(float4*)(op + 4) = make_float4(r[4], r[5], r[6], r[7]);
#pragma unroll
    for (int off = 32; off > 0; off >>= 1) {
        s += __shfl_down(s, off, 64);
        s2 += __shfl_down(s2, off, 64);
    }
    int wv = tx >> 6;
    if ((tx & 63) == 0) { sb[wv] = s; sb[4 + wv] = s2; }
    __syncthreads();
    if (tx == 0) {
        int slot = (b * 8 + (blockIdx.x & 7)) * 16;
        atomicAdd(&stats[slot], sb[0] + sb[1] + sb[2] + sb[3]);
        atomicAdd(&stats[slot + 1], sb[4] + sb[5] + sb[6] + sb[7]);
    }
}

// ---------------- NHWC bf16 dwconv3 + bias + relu -> bf16 ----------------
__global__ __launch_bounds__(256) void dwc_bf16_kernel(const unsigned short* __restrict__ in,
                                                       const float* __restrict__ wT,
                                                       const float* __restrict__ bias,
                                                       unsigned short* __restrict__ out) {
    int b = blockIdx.y, tx = threadIdx.x;
    int cg = tx & 15, pp = tx >> 4;
    int p = blockIdx.x * 16 + pp;
    int xx = p & 63, yy = p >> 6;
    int c0 = cg * 8;
    float acc[8];
#pragma unroll
    for (int j = 0; j < 8; ++j) acc[j] = bias[c0 + j];
#pragma unroll
    for (int dy = -1; dy <= 1; ++dy) {
        int y2 = yy + dy;
        if (y2 < 0 || y2 >= 64) continue;
#pragma unroll
        for (int dx = -1; dx <= 1; ++dx) {
            int x2 = xx + dx;
            if (x2 < 0 || x2 >= 64) continue;
            unsigned short v[8];
            *(uint4*)v = *(const uint4*)&in[((size_t)b * NPIX + y2 * 64 + x2) * 128 + c0];
            const float* wr = wT + ((dy + 1) * 3 + dx + 1) * 128 + c0;
#pragma unroll
            for (int j = 0; j < 8; ++j) acc[j] += b2f(v[j]) * wr[j];
        }
    }
    unsigned short o[8];
#pragma unroll
    for (int j = 0; j < 8; ++j) o[j] = f2b(fmaxf(acc[j], 0.f));
    *(uint4*)&out[((size_t)b * NPIX + p) * 128 + c0] = *(uint4*)o;
}

// ---------------- conv1x1 via bf16 MFMA, 128out x 64px tile (y-parallel form) ----------------
__global__ __launch_bounds__(256) void conv_mfma_kernel(const unsigned short* __restrict__ in_t,
                                                        const float* __restrict__ in_f32,
                                                        const float* __restrict__ gst,
                                                        const float* __restrict__ gg,
                                                        const float* __restrict__ gbta,
                                                        const unsigned short* __restrict__ w,
                                                        const float* __restrict__ bias,
                                                        const float* __restrict__ res,
                                                        float* __restrict__ out,
                                                        unsigned short* __restrict__ out_t,
                                                        unsigned short* __restrict__ out_t2,
                                                        int Cin, int Cout, int relu, int nchw) {
    __shared__ __align__(16) unsigned short A_s[128][136];
    __shared__ __align__(16) unsigned short B_s[64][136];
    int b = blockIdx.z, p0 = blockIdx.x * 64, o0 = blockIdx.y * 128;
    int tx = threadIdx.x;
    int wave = tx >> 6, lane = tx & 63;
    int wm = wave & 1, wn = wave >> 1;
    int quad = lane >> 4, l16 = lane & 15;

    float mu = 0.f, rr = 1.f;
    if (in_f32) {
        float su = 0.f, sq = 0.f;
#pragma unroll
        for (int sl = 0; sl < 8; ++sl) {
            su += gst[(b * 8 + sl) * 16];
            sq += gst[(b * 8 + sl) * 16 + 1];
        }
        const float n = 1.f / (float)(CDIM * NPIX);
        mu = su * n;
        float var = sq * n - mu * mu;
        rr = rsqrtf(var + EPSN);
    }

    f32x4 acc[4][2];
#pragma unroll
    for (int mt = 0; mt < 4; ++mt) {
#pragma unroll
        for (int r = 0; r < 4; ++r) {
            float bv = bias[o0 + wm * 64 + mt * 16 + quad * 4 + r];
#pragma unroll
            for (int nt = 0; nt < 2; ++nt) acc[mt][nt][r] = bv;
        }
    }

    for (int k0 = 0; k0 < Cin; k0 += 128) {
#pragma unroll
        for (int j = 0; j < 8; ++j) {
            int idx = tx + 256 * j;
            int row = idx >> 4, c16 = idx & 15;
            *(uint4*)&A_s[row][c16 * 8] =
                *(const uint4*)&w[(size_t)(o0 + row) * Cin + k0 + c16 * 8];
        }
        if (in_f32) {
#pragma unroll
            for (int j = 0; j < 4; ++j) {
                int idx = tx + 256 * j;
                int row = idx >> 4, c16 = idx & 15;
                int ch = c16 * 8;  // Cin==128
                const float* ip = &in_f32[((size_t)b * NPIX + p0 + row) * 128 + ch];
                float4 v0 = *(const float4*)ip;
                float4 v1 = *(const float4*)(ip + 4);
                unsigned short o[8];
                o[0] = f2b((v0.x - mu) * rr * gg[ch + 0] + gbta[ch + 0]);
                o[1] = f2b((v0.y - mu) * rr * gg[ch + 1] + gbta[ch + 1]);
                o[2] = f2b((v0.z - mu) * rr * gg[ch + 2] + gbta[ch + 2]);
                o[3] = f2b((v0.w - mu) * rr * gg[ch + 3] + gbta[ch + 3]);
                o[4] = f2b((v1.x - mu) * rr * gg[ch + 4] + gbta[ch + 4]);
                o[5] = f2b((v1.y - mu) * rr * gg[ch + 5] + gbta[ch + 5]);
                o[6] = f2b((v1.z - mu) * rr * gg[ch + 6] + gbta[ch + 6]);
                o[7] = f2b((v1.w - mu) * rr * gg[ch + 7] + gbta[ch + 7]);
                *(uint4*)&B_s[row][c16 * 8] = *(uint4*)o;
            }
        } else {
#pragma unroll
            for (int j = 0; j < 4; ++j) {
                int idx = tx + 256 * j;
                int row = idx >> 4, c16 = idx & 15;
                *(uint4*)&B_s[row][c16 * 8] =
                    *(const uint4*)&in_t[((size_t)b * NPIX + p0 + row) * Cin + k0 + c16 * 8];
            }
        }
        __syncthreads();
#pragma unroll
        for (int ks = 0; ks < 128; ks += 32) {
            short8 af[4], bf[2];
#pragma unroll
            for (int mt = 0; mt < 4; ++mt)
                af[mt] = *(const short8*)&A_s[wm * 64 + mt * 16 + l16][ks + quad * 8];
#pragma unroll
            for (int nt = 0; nt < 2; ++nt)
                bf[nt] = *(const short8*)&B_s[wn * 32 + nt * 16 + l16][ks + quad * 8];
#pragma unroll
            for (int mt = 0; mt < 4; ++mt)
#pragma unroll
                for (int nt = 0; nt < 2; ++nt)
                    acc[mt][nt] = __builtin_amdgcn_mfma_f32_16x16x32_bf16(
                        af[mt], bf[nt], acc[mt][nt], 0, 0, 0);
        }
        __syncthreads();
    }

    int dorelu = (relu == 1) || (relu == 2 && blockIdx.y == 0);
    if (out_t) {
#pragma unroll
        for (int mt = 0; mt < 4; ++mt) {
#pragma unroll
            for (int nt = 0; nt < 2; ++nt) {
                int p = p0 + wn * 32 + nt * 16 + l16;
                int ob = o0 + wm * 64 + mt * 16 + quad * 4;
                unsigned short* dbuf = out_t;
                int oc = ob;
                if (out_t2 && o0 >= 128) { dbuf = out_t2; oc = ob - 128; }
                ushort4 u;
                float v0 = acc[mt][nt][0], v1 = acc[mt][nt][1];
                float v2 = acc[mt][nt][2], v3 = acc[mt][nt][3];
                if (dorelu) { v0 = fmaxf(v0, 0.f); v1 = fmaxf(v1, 0.f);
                              v2 = fmaxf(v2, 0.f); v3 = fmaxf(v3, 0.f); }
                u.x = f2b(v0); u.y = f2b(v1); u.z = f2b(v2); u.w = f2b(v3);
                *(ushort4*)&dbuf[((size_t)b * NPIX + p) * Cout + oc] = u;
            }
        }
    } else if (!nchw) {
#pragma unroll
        for (int mt = 0; mt < 4; ++mt) {
#pragma unroll
            for (int nt = 0; nt < 2; ++nt) {
                int p = p0 + wn * 32 + nt * 16 + l16;
                int ob = o0 + wm * 64 + mt * 16 + quad * 4;
                size_t ix = ((size_t)b * NPIX + p) * Cout + ob;
                float4 v = make_float4(acc[mt][nt][0], acc[mt][nt][1],
                                       acc[mt][nt][2], acc[mt][nt][3]);
                if (dorelu) { v.x = fmaxf(v.x, 0.f); v.y = fmaxf(v.y, 0.f);
                              v.z = fmaxf(v.z, 0.f); v.w = fmaxf(v.w, 0.f); }
                if (res) {
                    float4 rv = *(const float4*)&res[ix];
                    v.x += rv.x; v.y += rv.y; v.z += rv.z; v.w += rv.w;
                }
                *(float4*)&out[ix] = v;
            }
        }
    } else {
        float* outb = out + (size_t)b * Cout * NPIX;
#pragma unroll
        for (int mt = 0; mt < 4; ++mt) {
#pragma unroll
            for (int nt = 0; nt < 2; ++nt) {
                int p = p0 + wn * 32 + nt * 16 + l16;
                int ob = o0 + wm * 64 + mt * 16 + quad * 4;
                float4 rv = make_float4(0.f, 0.f, 0.f, 0.f);
                if (res) rv = *(const float4*)&res[((size_t)b * NPIX + p) * 128 + ob];
#pragma unroll
                for (int r = 0; r < 4; ++r) {
                    float v = acc[mt][nt][r];
                    if (dorelu) v = fmaxf(v, 0.f);
                    v += (r == 0 ? rv.x : r == 1 ? rv.y : r == 2 ? rv.z : rv.w);
                    outb[(size_t)(ob + r) * NPIX + p] = v;
                }
            }
        }
    }
}

// ---------------- MFMA window attention, both orientations in one launch ----------------
// q pre-scaled by log2(e) -> native exp2; row-sum via ones-row at PV A row 16 (o_acc[8]).
// K staged in LDS (Kt[256][24], 48B rows: bank-conflict-free b128 reads); V transposed in
// Vt[18][264]: rows 0-15 = V dims, row 16 = ones (row-sum), row 17 = SHARED zero row —
// lanes l32>=17 all read row 17 (same-address LDS broadcast, conflict-free) via
// vrow = min(l32,17), computed once. This cut LDS 29.2->21.8 KB => 7 blocks/CU (was 5),
// attacking the ~55% stall time (occupancy was 31-36%).
// a0/a1 now bf16: consumer m_t is bf16 anyway; saves ~25MB HBM across attn+mul3.
// nt outer / both q-slices inner; P redistribution via v_permlane32_swap_b32.
__global__ __launch_bounds__(256) void attn_dual_kernel(const unsigned short* __restrict__ t_t,
                                                        unsigned short* __restrict__ a0,
                                                        unsigned short* __restrict__ a1) {
    __shared__ __align__(16) unsigned short Vt[18][264];
    __shared__ __align__(16) unsigned short Kt[256][24];
    int wi = blockIdx.x, head = blockIdx.y;
    int z = blockIdx.z;
    int b = z >> 1, which = z & 1;
    int qoff = which ? 384 : 0;
    int koff = which ? 512 : 128;
    int mode = which;
    unsigned short* a_out = which ? a1 : a0;
    int tx = threadIdx.x;
    int wave = tx >> 6, l = tx & 63;
    int l32 = l & 31, half = l >> 5;
    const size_t base = (size_t)b * NPIX;
    const int hc = head * 16;

    {
        int p = tok2pix(mode, wi, tx);
        const unsigned short* vp = &t_t[(base + p) * 640 + 256 + hc];
        const unsigned short* kp = &t_t[(base + p) * 640 + koff + hc];
        unsigned short tmp[16];
        *(uint4*)&tmp[0] = *(const uint4*)vp;
        *(uint4*)&tmp[8] = *(const uint4*)(vp + 8);
        uint4 k0 = *(const uint4*)kp;
        uint4 k1 = *(const uint4*)(kp + 8);
        *(uint4*)&Kt[tx][0] = k0;
        *(uint4*)&Kt[tx][8] = k1;
#pragma unroll
        for (int d = 0; d < 16; ++d) Vt[d][tx] = tmp[d];
        Vt[16][tx] = (unsigned short)0x3F80;  // bf16 1.0 — row-sum row
        Vt[17][tx] = 0;                       // shared zero row for lanes l32>=17
    }
    __syncthreads();

    f32x16 zzero;
#pragma unroll
    for (int r = 0; r < 16; ++r) zzero[r] = 0.f;

    int vrow = (l32 < 17) ? l32 : 17;   // loop-invariant; lanes >=17 broadcast zero row
    const unsigned short* vbase = &Vt[vrow][0];

    const unsigned short* qb = t_t + base * 640 + hc + half * 8 + qoff;

    int qp0 = tok2pix(mode, wi, (0 * 4 + wave) * 32 + l32);
    int qp1 = tok2pix(mode, wi, (1 * 4 + wave) * 32 + l32);
    short8 qf0 = *(const short8*)&qb[(size_t)qp0 * 640];
    short8 qf1 = *(const short8*)&qb[(size_t)qp1 * 640];
    f32x16 oa0 = zzero, oa1 = zzero;

#pragma unroll
    for (int nt = 0; nt < 8; ++nt) {
        short8 kf = *(const short8*)&Kt[nt * 32 + l32][half * 8];
        short8 vf0 = *(const short8*)&vbase[nt * 32 + half * 8];
        short8 vf1 = *(const short8*)&vbase[nt * 32 + 16 + half * 8];
#pragma unroll
        for (int qi = 0; qi < 2; ++qi) {
            short8 qf = (qi == 0) ? qf0 : qf1;
            f32x16 s = __builtin_amdgcn_mfma_f32_32x32x16_bf16(kf, qf, zzero, 0, 0, 0);
            unsigned int pk[8];
#pragma unroll
            for (int i = 0; i < 8; ++i) {
                float e0 = __builtin_amdgcn_exp2f(s[2 * i]);
                float e1 = __builtin_amdgcn_exp2f(s[2 * i + 1]);
                pk[i] = __builtin_amdgcn_perm(__float_as_uint(e1), __float_as_uint(e0),
                                              0x07060302u);
            }
            // redistribute halves: (u0[0],u0[2]) = swap(pk0,pk2), etc.
            pl32swap(pk[0], pk[2]);
            pl32swap(pk[1], pk[3]);
            pl32swap(pk[4], pk[6]);
            pl32swap(pk[5], pk[7]);
            unsigned int u0[4] = {pk[0], pk[1], pk[2], pk[3]};
            unsigned int u1[4] = {pk[4], pk[5], pk[6], pk[7]};
            if (qi == 0) {
                oa0 = __builtin_amdgcn_mfma_f32_32x32x16_bf16(vf0, *(short8*)u0, oa0, 0, 0, 0);
                oa0 = __builtin_amdgcn_mfma_f32_32x32x16_bf16(vf1, *(short8*)u1, oa0, 0, 0, 0);
            } else {
                oa1 = __builtin_amdgcn_mfma_f32_32x32x16_bf16(vf0, *(short8*)u0, oa1, 0, 0, 0);
                oa1 = __builtin_amdgcn_mfma_f32_32x32x16_bf16(vf1, *(short8*)u1, oa1, 0, 0, 0);
            }
        }
    }

    // epilogue for both q-slices: row 16 of PV output = sum_t P[t][col] (r=8)
#pragma unroll
    for (int qi = 0; qi < 2; ++qi) {
        f32x16 oc = (qi == 0) ? oa0 : oa1;
        int qp = (qi == 0) ? qp0 : qp1;
        float rs = oc[8];
        rs += __shfl_xor(rs, 32, 64);
        float rinv = 1.f / rs;
        // d = (r&3) + 8*(r>>2) + 4*half  ->  two contiguous ushort4 runs
        unsigned short* dst = a_out + (base + qp) * 128 + hc + 4 * half;
        ushort4 s0, s1;
        s0.x = f2b(oc[0] * rinv); s0.y = f2b(oc[1] * rinv);
        s0.z = f2b(oc[2] * rinv); s0.w = f2b(oc[3] * rinv);
        s1.x = f2b(oc[4] * rinv); s1.y = f2b(oc[5] * rinv);
        s1.z = f2b(oc[6] * rinv); s1.w = f2b(oc[7] * rinv);
        *(ushort4*)dst = s0;
        *(ushort4*)(dst + 8) = s1;
    }
}

// ---------------- m_t = bf16((a0 + a1 + cpe(v0)) * act_res)  (all NHWC, a0/a1 bf16) ----------------
__global__ __launch_bounds__(256) void mul3_cpe_kernel(const unsigned short* __restrict__ a0,
                                                       const unsigned short* __restrict__ a1,
                                                       const unsigned short* __restrict__ act,
                                                       const unsigned short* __restrict__ t_t,
                                                       const float* __restrict__ wT,
                                                       const float* __restrict__ bsum,
                                                       unsigned short* __restrict__ dst) {
    int b = blockIdx.y;
    int tx = threadIdx.x;
    int cg = tx & 15, pp = tx >> 4;
    int p = blockIdx.x * 16 + pp;
    int xx = p & 63, yy = p >> 6;
    int c0 = cg * 8;
    float acc[8];
#pragma unroll
    for (int j = 0; j < 8; ++j) acc[j] = bsum[c0 + j];
#pragma unroll
    for (int dy = -1; dy <= 1; ++dy) {
        int y2 = yy + dy;
        if (y2 < 0 || y2 >= 64) continue;
#pragma unroll
        for (int dx = -1; dx <= 1; ++dx) {
            int x2 = xx + dx;
            if (x2 < 0 || x2 >= 64) continue;
            int pn = y2 * 64 + x2;
            unsigned short v[8];
            *(uint4*)v = *(const uint4*)&t_t[((size_t)b * NPIX + pn) * 640 + 256 + c0];
            const float* wr = wT + ((dy + 1) * 3 + dx + 1) * 128 + c0;
#pragma unroll
            for (int j = 0; j < 8; ++j) acc[j] += b2f(v[j]) * wr[j];
        }
    }
    size_t base = ((size_t)b * NPIX + p) * 128 + c0;
    unsigned short xa[8], ya[8], t[8];
    *(uint4*)xa = *(const uint4*)&a0[base];
    *(uint4*)ya = *(const uint4*)&a1[base];
    *(uint4*)t  = *(const uint4*)&act[base];
    unsigned short r[8];
#pragma unroll
    for (int j = 0; j < 8; ++j)
        r[j] = f2b((b2f(xa[j]) + b2f(ya[j]) + acc[j]) * b2f(t[j]));
    *(uint4*)&dst[base] = *(uint4*)r;
}

extern "C" void kernel_launch(void* const* d_in, const int* in_sizes, int n_in,
                              void* d_out, int out_size, void* d_ws, size_t ws_size,
                              hipStream_t stream) {
    const float* x       = (const float*)d_in[0];
    const float* eca_w   = (const float*)d_in[1];
    const float* esa_al  = (const float*)d_in[2];
    const float* cpe1_w  = (const float*)d_in[3];  const float* cpe1_b = (const float*)d_in[4];
    const float* g1      = (const float*)d_in[5];  const float* b1     = (const float*)d_in[6];
    const float* actp_w  = (const float*)d_in[7];  const float* actp_b = (const float*)d_in[8];
    const float* inp_w   = (const float*)d_in[9];  const float* inp_b  = (const float*)d_in[10];
    const float* dwc_w   = (const float*)d_in[11]; const float* dwc_b  = (const float*)d_in[12];
    const float* qkv_w   = (const float*)d_in[13]; const float* qkv_b  = (const float*)d_in[14];
    const float* eaax_w  = (const float*)d_in[15]; const float* eaax_b = (const float*)d_in[16];
    const float* eaay_w  = (const float*)d_in[17]; const float* eaay_b = (const float*)d_in[18];
    const float* outp_w  = (const float*)d_in[19]; const float* outp_b = (const float*)d_in[20];
    const float* cpe2_w  = (const float*)d_in[21]; const float* cpe2_b = (const float*)d_in[22];
    const float* g2      = (const float*)d_in[23]; const float* b2     = (const float*)d_in[24];
    const float* mlp1_w  = (const float*)d_in[25]; const float* mlp1_b = (const float*)d_in[26];
    const float* mlp2_w  = (const float*)d_in[27]; const float* mlp2_b = (const float*)d_in[28];

    float* ws = (float*)d_ws;
    unsigned short* U = (unsigned short*)d_ws;
    const size_t E = (size_t)BATCH * CDIM * NPIX;  // 4,194,304

    float* y_nhwc  = ws;                // [0,E) floats: esa out (dead after cpe1)
    unsigned short* a0b = U;            // bf16 [0,0.5E) floats — reuses y_nhwc region
    float* sc_nhwc = ws + E;            // [E,2E) shortcut (live to outp)
    unsigned short* act_t = U + 5 * E;  // [2.5E,3E)
    unsigned short* it_t  = U + 6 * E;  // [3E,3.5E)
    unsigned short* tin_t = U + 7 * E;  // [3.5E,4E)
    unsigned short* a1b   = U + 8 * E;  // bf16 [4E,4.5E) floats
    unsigned short* t_t   = U + 10 * E; // [5E,7.5E)
    unsigned short* m_t   = U + 15 * E; // [7.5E,8E)
    float* out_nhwc = ws + 8 * E;       // [8E,9E)
    float* out2    = ws + 2 * E;        // [2E,3E)  (act_t dead by then)
    unsigned short* hid_t = U + 10 * E; // [5E,7E)  (t_t dead after mul3_cpe)
    unsigned short* wpool = U + 20 * E; // 262144 bf16
    unsigned short* wq  = wpool;
    unsigned short* wm1 = wpool + 81920;
    unsigned short* wm2 = wpool + 147456;
    unsigned short* wai = wpool + 212992;   // actp rows 0-127, inp rows 128-255 (contiguous)
    unsigned short* wo  = wpool + 245760;
    float* fb     = ws + 10 * E + 131072;
    float* meanb  = fb;            // 1024
    float* gstats = fb + 2048;     // 2048: gn1 [0,1024), gn2 [1024,2048)
    float* qb_r   = fb + 4096;     // 640
    float* wsT    = fb + 4736;     // 1152
    float* bsum   = fb + 5888;     // 128
    float* cpe1T  = fb + 6016;     // 1152
    float* dwcT   = fb + 7168;     // 1152
    float* cpe2T  = fb + 8320;     // 1152
    float* abi    = fb + 9472;     // 256

    convert_w_kernel<<<1054, 256, 0, stream>>>(qkv_w, mlp1_w, mlp2_w, actp_w, inp_w, outp_w,
                                               qkv_b, eaax_w, eaax_b, eaay_w, eaay_b,
                                               cpe1_w, dwc_w, cpe2_w, actp_b, inp_b,
                                               wpool, qb_r, wsT, bsum, cpe1T, dwcT, cpe2T, abi,
                                               gstats);

    // 1) ECA + ESA (gate inline) with transpose -> y (f32 NHWC)
    mean_bc_kernel<<<BATCH * CDIM, 256, 0, stream>>>(x, meanb);
    esa_tr_kernel<<<dim3(64, BATCH), 256, 0, stream>>>(x, meanb, eca_w, esa_al, y_nhwc);
    // 2) shortcut = y + cpe1(y), fused GN1 stats
    cpe_f32_kernel<<<dim3(256, BATCH), 256, 0, stream>>>(y_nhwc, cpe1T, cpe1_b, sc_nhwc, gstats);
    // 3+4+5a) merged actp+inp conv with fused GN1 apply: sc_nhwc -> act_t (relu), it_t
    conv_mfma_kernel<<<dim3(64, 2, BATCH), 256, 0, stream>>>(nullptr, sc_nhwc, gstats, g1, b1,
                                                             wai, abi, nullptr, nullptr,
                                                             act_t, it_t, 128, 128, 2, 0);
    // 5b) tin = relu(dwc(it))
    dwc_bf16_kernel<<<dim3(256, BATCH), 256, 0, stream>>>(it_t, dwcT, dwc_b, tin_t);
    // 6) qkv -> t_t (bf16 NHWC, 640 grouped; q groups pre-scaled by log2e)
    conv_mfma_kernel<<<dim3(64, 5, BATCH), 256, 0, stream>>>(tin_t, nullptr, nullptr, nullptr,
                                                             nullptr, wq, qb_r, nullptr, nullptr,
                                                             t_t, nullptr, 128, 640, 0, 0);
    // 7) both attentions -> a0, a1 (bf16)
    attn_dual_kernel<<<dim3(16, 8, 2 * BATCH), 256, 0, stream>>>(t_t, a0b, a1b);
    // 8) m_t = bf16((a0+a1+cpe(v0))*act) ; out = outp(m) + shortcut -> out_nhwc
    mul3_cpe_kernel<<<dim3(256, BATCH), 256, 0, stream>>>(a0b, a1b, act_t, t_t, wsT, bsum, m_t);
    conv_mfma_kernel<<<dim3(64, 1, BATCH), 256, 0, stream>>>(m_t, nullptr, nullptr, nullptr,
                                                             nullptr, wo, outp_b, sc_nhwc,
                                                             out_nhwc, nullptr, nullptr,
                                                             128, 128, 0, 0);
    // 9) out2 = out + cpe2(out), fused GN2 stats
    cpe_f32_kernel<<<dim3(256, BATCH), 256, 0, stream>>>(out_nhwc, cpe2T, cpe2_b, out2,
                                                         gstats + 1024);
    // 10+11) mlp1 with fused GN2 apply -> hid_t ; mlp2 + out2 residual -> d_out (NCHW)
    conv_mfma_kernel<<<dim3(64, 4, BATCH), 256, 0, stream>>>(nullptr, out2, gstats + 1024, g2, b2,
                                                             wm1, mlp1_b, nullptr, nullptr,
                                                             hid_t, nullptr, 128, 512, 1, 0);
    conv_mfma_kernel<<<dim3(64, 1, BATCH), 256, 0, stream>>>(hid_t, nullptr, nullptr, nullptr,
                                                             nullptr, wm2, mlp2_b, out2,
                                                             (float*)d_out, nullptr, nullptr,
                                                             512, 128, 0, 1);
}